// Round 4
// baseline (3335.087 us; speedup 1.0000x reference)
//
#include <hip/hip_runtime.h>

// ---------------- problem constants ----------------
#define MUL0 64
#define MUL1 32
#define NBASIS 10
#define FCH 100
#define WNUMEL 224   // 2*MUL0 + 3*MUL1
#define MIDS 96      // MUL0 + MUL1
#define MIDV 128     // MUL0 + 2*MUL1
#define GNODES 16    // dst nodes per workgroup in k_edge_agg

// weight table offsets inside ws (floats), in d_in[7..15] order
#define OFF_W1   0        // W_fc1  10x100  (1000)
#define OFF_W2   1000     // W_fc2  100x224 (22400)
#define OFF_WSCS 23400    // W_sc_s 64x64   (4096)
#define OFF_WSCV 27496    // W_sc_v 32x32   (1024)
#define OFF_WL1S 28520    // W_l1_s 64x64   (4096)
#define OFF_WL1V 32616    // W_l1_v 32x32   (1024)
#define OFF_WL2S 33640    // W_l2_s 96x64   (6144)
#define OFF_WL2V 39784    // W_l2_v 128x32  (4096)
#define OFF_WL3  43880    // W_l3   96x1    (96)
#define OFF_WEND 43976
#define OFF_FLAG 43980    // dtype flag (int) lives here, inside the pad
#define OFF_DYN  44032    // padded start of per-node buffers

// ---------------- helpers ----------------
__device__ __forceinline__ float bf2f(unsigned short h) {
    unsigned int u = ((unsigned int)h) << 16;
    float f; __builtin_memcpy(&f, &u, 4); return f;
}
__device__ __forceinline__ unsigned short f2bf(float f) {
    unsigned int u; __builtin_memcpy(&u, &f, 4);
    u += 0x7fffu + ((u >> 16) & 1u);   // round-to-nearest-even
    return (unsigned short)(u >> 16);
}
__device__ __forceinline__ float lo2f(unsigned int w) {
    unsigned int u = w << 16; float f; __builtin_memcpy(&f, &u, 4); return f;
}
__device__ __forceinline__ float hi2f(unsigned int w) {
    unsigned int u = w & 0xffff0000u; float f; __builtin_memcpy(&f, &u, 4); return f;
}
__device__ __forceinline__ float fast_silu(float x) {
    return x * __builtin_amdgcn_rcpf(1.0f + __expf(-x));
}
// dtype-generic load/store: BF=true -> bf16 stream, BF=false -> fp32 stream
template<bool BF>
__device__ __forceinline__ float ldf(const void* p, size_t i) {
    if constexpr (BF) return bf2f(((const unsigned short*)p)[i]);
    else              return ((const float*)p)[i];
}
template<bool BF>
__device__ __forceinline__ void stf(void* p, size_t i, float v) {
    if constexpr (BF) ((unsigned short*)p)[i] = f2bf(v);
    else              ((float*)p)[i] = v;
}

// ---------------- kernel P: dtype probe ----------------
__global__ void k_probe(const unsigned int* __restrict__ attr_bits, int* __restrict__ flag)
{
    if (blockIdx.x == 0 && threadIdx.x == 0)
        *flag = (attr_bits[0] == 0x3F803F80u) ? 1 : 0;
}

// ---------------- kernel 0: convert all weights -> fp32 in ws ----------------
__global__ __launch_bounds__(256) void k_convert(
    const void* __restrict__ a0, const void* __restrict__ a1,
    const void* __restrict__ a2, const void* __restrict__ a3,
    const void* __restrict__ a4, const void* __restrict__ a5,
    const void* __restrict__ a6, const void* __restrict__ a7,
    const void* __restrict__ a8, float* __restrict__ wsf,
    const int* __restrict__ flag)
{
    int i = blockIdx.x * 256 + threadIdx.x;
    if (i >= OFF_WEND) return;
    const void* p; int off = i;
    if      (i < OFF_W2)   { p = a0; }
    else if (i < OFF_WSCS) { p = a1; off = i - OFF_W2; }
    else if (i < OFF_WSCV) { p = a2; off = i - OFF_WSCS; }
    else if (i < OFF_WL1S) { p = a3; off = i - OFF_WSCV; }
    else if (i < OFF_WL1V) { p = a4; off = i - OFF_WL1S; }
    else if (i < OFF_WL2S) { p = a5; off = i - OFF_WL1V; }
    else if (i < OFF_WL2V) { p = a6; off = i - OFF_WL2S; }
    else if (i < OFF_WL3)  { p = a7; off = i - OFF_WL2V; }
    else                   { p = a8; off = i - OFF_WL3; }
    wsf[i] = (*flag) ? ldf<true>(p, off) : ldf<false>(p, off);
}

// ---------------- CSR build: histogram / scan / place ----------------
__global__ __launch_bounds__(256) void k_hist(
    const int* __restrict__ edst, int* __restrict__ cnt, int Ecnt)
{
    int e = blockIdx.x * 256 + threadIdx.x;
    if (e < Ecnt) atomicAdd(&cnt[edst[e]], 1);
}

__device__ __forceinline__ int wave_incl_scan(int v) {
    int lane = threadIdx.x & 63;
    #pragma unroll
    for (int d = 1; d < 64; d <<= 1) {
        int t = __shfl_up(v, d, 64);
        if (lane >= d) v += t;
    }
    return v;
}

// single workgroup, 1024 threads: exclusive scan of cnt -> row_start, zero cur
__global__ __launch_bounds__(1024) void k_scan(
    const int* __restrict__ cnt, int* __restrict__ row_start,
    int* __restrict__ cur, int Nn)
{
    __shared__ int wsum[16];
    __shared__ int s_off, s_tot;
    int tid = threadIdx.x, lane = tid & 63, wid = tid >> 6;
    if (tid == 0) s_off = 0;
    __syncthreads();
    for (int base = 0; base < Nn; base += 1024) {
        int i = base + tid;
        int v = (i < Nn) ? cnt[i] : 0;
        int incl = wave_incl_scan(v);
        if (lane == 63) wsum[wid] = incl;
        __syncthreads();
        if (wid == 0) {
            int wv = (lane < 16) ? wsum[lane] : 0;
            int wincl = wave_incl_scan(wv);
            if (lane < 16) wsum[lane] = wincl - wv;   // exclusive wave offset
            if (lane == 15) s_tot = wincl;            // tile total
        }
        __syncthreads();
        int excl = s_off + wsum[wid] + incl - v;
        if (i < Nn) { row_start[i] = excl; cur[i] = 0; }
        __syncthreads();
        if (tid == 0) s_off += s_tot;
        __syncthreads();
    }
    if (threadIdx.x == 0) row_start[Nn] = s_off;
}

__global__ __launch_bounds__(256) void k_place(
    const int* __restrict__ edst, const int* __restrict__ row_start,
    int* __restrict__ cur, int* __restrict__ perm, int Ecnt)
{
    int e = blockIdx.x * 256 + threadIdx.x;
    if (e < Ecnt) {
        int d = edst[e];
        int pos = row_start[d] + atomicAdd(&cur[d], 1);
        perm[pos] = e;
    }
}

// ---------------- kernel 1: node precompute f_s, f_v ----------------
template<bool BF>
__device__ __forceinline__ void node_pre_body(
    const void* __restrict__ ns, const void* __restrict__ nv,
    const void* __restrict__ attr,
    const float* __restrict__ Wl1s, const float* __restrict__ Wl1v,
    float* __restrict__ f_s, float* __restrict__ f_v, int Nn)
{
    int i = blockIdx.x * 256 + threadIdx.x;
    int stotal = Nn * MUL0;
    if (i < stotal) {
        int n = i >> 6, j = i & 63;
        float a = 0.f;
        #pragma unroll
        for (int u = 0; u < MUL0; u++)
            a = fmaf(ldf<BF>(ns, (size_t)n * MUL0 + u), Wl1s[u * MUL0 + j], a);
        f_s[i] = a * ldf<BF>(attr, n);
    } else {
        int m = i - stotal;
        if (m >= Nn * MUL1 * 3) return;
        int n = m / 96; int idx = m - n * 96;
        int vi = idx / 3; int c = idx - vi * 3;
        float a = 0.f;
        #pragma unroll
        for (int u = 0; u < MUL1; u++)
            a = fmaf(ldf<BF>(nv, (size_t)n * 96 + u * 3 + c), Wl1v[u * MUL1 + vi], a);
        f_v[m] = a * ldf<BF>(attr, n);
    }
}
__global__ __launch_bounds__(256) void k_node_pre(
    const void* ns, const void* nv, const void* attr,
    const float* Wl1s, const float* Wl1v,
    float* f_s, float* f_v, int Nn, const int* flag)
{
    if (*flag) node_pre_body<true >(ns, nv, attr, Wl1s, Wl1v, f_s, f_v, Nn);
    else       node_pre_body<false>(ns, nv, attr, Wl1s, Wl1v, f_s, f_v, Nn);
}

// ---------------- kernel 2: dst-grouped edge aggregation ----------------
// wg owns GNODES consecutive dsts; edges from dst-sorted perm (contiguous).
// W2 staged per 32-col chunk into LDS (broadcast reads — off the scalar pipe,
// which round-3 counters showed was the latency bottleneck: VALUBusy 8%).
// h[100] lives in 50 packed-bf16 VGPRs. Accumulate via LDS atomics; write agg
// once per node. Fused angle epilogue.
#define ACC_STRIDE 481   // 480 feats + 1 pad

template<bool BF>
__device__ void edge_agg_body(
    const void* __restrict__ escal, const void* __restrict__ eattr,
    const void* __restrict__ attr,
    const int* __restrict__ esrc, const int* __restrict__ edst,
    const int* __restrict__ row_start, const int* __restrict__ perm,
    const float* __restrict__ W1f, const float* __restrict__ W2f,
    const float* __restrict__ Wl3,
    const float* __restrict__ f_s, const float* __restrict__ f_v,
    float* __restrict__ agg_s, float* __restrict__ agg_v,
    float* __restrict__ cosb, float* __restrict__ sinb, int Nn,
    float* __restrict__ w1s, float* __restrict__ w2s, float* __restrict__ accum)
{
    const int tid   = threadIdx.x;
    const int gbase = blockIdx.x * GNODES;
    const int gend  = (gbase + GNODES < Nn) ? (gbase + GNODES) : Nn;

    // zero LDS accumulator + stage W1 (4 KB)
    for (int i = tid; i < GNODES * ACC_STRIDE; i += 256) accum[i] = 0.f;
    for (int i = tid; i < NBASIS * FCH; i += 256) w1s[i] = W1f[i];
    __syncthreads();

    const int e_start = row_start[gbase];
    const int e_end   = row_start[gend];

    for (int base = e_start; base < e_end; base += 256) {
        const int idx = base + tid;
        const bool active = (idx < e_end);
        const bool wact = (__ballot(active) != 0ull);   // wave-uniform

        int src = 0, dl = 0;
        unsigned int hpack[50];
        float y0 = 0.f, y1x = 0.f, y1y = 0.f, y1z = 0.f;

        if (wact) {
            const int e = perm[active ? idx : (e_end - 1)];
            src = esrc[e];
            dl  = edst[e] - gbase;

            float es[NBASIS];
            #pragma unroll
            for (int k = 0; k < NBASIS; k++) es[k] = ldf<BF>(escal, (size_t)e * NBASIS + k);
            y0  = ldf<BF>(eattr, (size_t)e * 4 + 0);
            y1x = ldf<BF>(eattr, (size_t)e * 4 + 1);
            y1y = ldf<BF>(eattr, (size_t)e * 4 + 2);
            y1z = ldf<BF>(eattr, (size_t)e * 4 + 3);

            // ---- FC1 from LDS W1 (broadcast reads), h -> 50 packed VGPRs ----
#define FC1_BLK(JB, CW) do {                                                \
            float acc[CW];                                                  \
            _Pragma("unroll") for (int j = 0; j < CW; j++) acc[j] = 0.f;    \
            _Pragma("unroll") for (int k = 0; k < NBASIS; k++) {            \
                float ek = es[k];                                           \
                _Pragma("unroll") for (int j = 0; j < CW; j++)              \
                    acc[j] = fmaf(ek, w1s[k * FCH + (JB) + j], acc[j]);     \
            }                                                               \
            _Pragma("unroll") for (int j = 0; j < CW; j += 2) {             \
                float a = fast_silu(acc[j]);                                \
                float b = fast_silu(acc[j + 1]);                            \
                hpack[((JB) + j) >> 1] =                                    \
                    (unsigned int)f2bf(a) | ((unsigned int)f2bf(b) << 16);  \
            }                                                               \
        } while (0)
            FC1_BLK(0, 32);
            FC1_BLK(32, 32);
            FC1_BLK(64, 32);
            FC1_BLK(96, 4);
#undef FC1_BLK
        }

        const float invn = 0.25f;                 // 1/sqrt(16)
        const float y0i  = y0 * invn;
        const float* fs_row = f_s + (size_t)src * MUL0;
        const float* fv_row = f_v + (size_t)src * 96;
        float* arow = accum + dl * ACC_STRIDE;

        // ---- 7 chunks: stage W2 cols [jb,jb+32) -> LDS; compute; consume ----
        for (int c = 0; c < 7; c++) {
            const int jb = c * 32;
            __syncthreads();
            #pragma unroll
            for (int t = 0; t < 13; t++) {          // 13*256 >= 3200
                int i = t * 256 + tid;
                if (i < FCH * 32)
                    w2s[i] = W2f[(size_t)(i >> 5) * WNUMEL + jb + (i & 31)];
            }
            __syncthreads();
            if (!wact) continue;                     // all waves still hit both barriers

            float w[32];
            #pragma unroll
            for (int j = 0; j < 32; j++) w[j] = 0.f;
            #pragma unroll 2
            for (int p = 0; p < 50; p++) {
                float h0 = lo2f(hpack[p]);
                float h1 = hi2f(hpack[p]);
                const float* r0 = w2s + 2 * p * 32;  // broadcast LDS reads
                #pragma unroll
                for (int j = 0; j < 32; j++)
                    w[j] = fmaf(h0, r0[j], fmaf(h1, r0[32 + j], w[j]));
            }

            if (!active) continue;
            switch (c) {
            case 0: case 1: {                        // A: w00*s*y0 -> feat 0..63
                const int j0 = jb;
                #pragma unroll
                for (int j = 0; j < 32; j++)
                    atomicAdd(&arow[j0 + j], w[j] * fs_row[j0 + j] * y0i);
                break; }
            case 2: case 3: {                        // B: w01*s (x) y1 -> feat 96+(0..63)*3
                const int j0 = jb - 64;
                #pragma unroll
                for (int j = 0; j < 32; j++) {
                    float b = w[j] * fs_row[j0 + j] * invn;
                    float* p2 = arow + 96 + (j0 + j) * 3;
                    atomicAdd(p2 + 0, b * y1x);
                    atomicAdd(p2 + 1, b * y1y);
                    atomicAdd(p2 + 2, b * y1z);
                }
                break; }
            case 4: {                                // C: w10*v*y0 -> feat 96+(64..95)*3
                #pragma unroll
                for (int u = 0; u < 32; u++) {
                    float b = w[u] * y0i;
                    const float* vp = fv_row + u * 3;
                    float* p2 = arow + 96 + (64 + u) * 3;
                    atomicAdd(p2 + 0, b * vp[0]);
                    atomicAdd(p2 + 1, b * vp[1]);
                    atomicAdd(p2 + 2, b * vp[2]);
                }
                break; }
            case 5: {                                // D: w11s*dot(v,y1)/sqrt3 -> feat 64..95
                const float c3 = 0.25f * 0.57735026918962576451f;
                #pragma unroll
                for (int u = 0; u < 32; u++) {
                    const float* vp = fv_row + u * 3;
                    float d = vp[0] * y1x + vp[1] * y1y + vp[2] * y1z;
                    atomicAdd(&arow[64 + u], w[u] * d * c3);
                }
                break; }
            default: {                               // E: w11v*cross(v,y1)/sqrt2 -> feat 96+(96..127)*3
                const float c2 = 0.25f * 0.70710678118654752440f;
                #pragma unroll
                for (int u = 0; u < 32; u++) {
                    const float* vp = fv_row + u * 3;
                    float v0 = vp[0], v1 = vp[1], v2 = vp[2];
                    float cx = v1 * y1z - v2 * y1y;
                    float cy = v2 * y1x - v0 * y1z;
                    float cz = v0 * y1y - v1 * y1x;
                    float b = w[u] * c2;
                    float* p2 = arow + 96 + (96 + u) * 3;
                    atomicAdd(p2 + 0, b * cx);
                    atomicAdd(p2 + 1, b * cy);
                    atomicAdd(p2 + 2, b * cz);
                }
                break; }
            }
        }
    }
    __syncthreads();

    // writeback: agg_s / agg_v (each node owned exclusively by this wg)
    for (int i = tid; i < GNODES * 480; i += 256) {
        int dl = i / 480, f = i - dl * 480;
        int n = gbase + dl;
        if (n >= Nn) continue;
        float v = accum[dl * ACC_STRIDE + f];
        if (f < 96) agg_s[(size_t)n * MIDS + f] = v;
        else        agg_v[(size_t)n * (MIDV * 3) + (f - 96)] = v;
    }
    // fused angle epilogue
    if (tid < GNODES) {
        int n = gbase + tid;
        if (n < Nn) {
            const float* ar = accum + tid * ACC_STRIDE;
            float a = 0.f;
            #pragma unroll
            for (int f = 0; f < MIDS; f++) a = fmaf(ar[f], Wl3[f], a);
            a = 0.1f * a * ldf<BF>(attr, n);
            cosb[n] = __cosf(a);
            sinb[n] = __sinf(a);
        }
    }
}

__global__ __launch_bounds__(256) void k_edge_agg(
    const void* escal, const void* eattr, const void* attr,
    const int* esrc, const int* edst,
    const int* row_start, const int* perm,
    const float* W1f, const float* W2f, const float* Wl3,
    const float* f_s, const float* f_v,
    float* agg_s, float* agg_v, float* cosb, float* sinb, int Nn,
    const int* flag)
{
    __shared__ float w1s[NBASIS * FCH];            // 4 KB
    __shared__ float w2s[FCH * 32];                // 12.8 KB
    __shared__ float accum[GNODES * ACC_STRIDE];   // 30.8 KB -> total 47.6 KB (3 wg/CU)
    if (*flag) edge_agg_body<true >(escal, eattr, attr, esrc, edst, row_start, perm,
                                    W1f, W2f, Wl3, f_s, f_v, agg_s, agg_v, cosb, sinb, Nn,
                                    w1s, w2s, accum);
    else       edge_agg_body<false>(escal, eattr, attr, esrc, edst, row_start, perm,
                                    W1f, W2f, Wl3, f_s, f_v, agg_s, agg_v, cosb, sinb, Nn,
                                    w1s, w2s, accum);
}

// ---------------- kernel 4: final output ----------------
template<bool BF>
__device__ __forceinline__ void final_body(
    const void* __restrict__ ns, const void* __restrict__ nv,
    const void* __restrict__ attr,
    const float* __restrict__ Wscs, const float* __restrict__ Wscv,
    const float* __restrict__ Wl2s, const float* __restrict__ Wl2v,
    const float* __restrict__ agg_s, const float* __restrict__ agg_v,
    const float* __restrict__ cosb, const float* __restrict__ sinb,
    void* __restrict__ out, int Nn)
{
    int i = blockIdx.x * 256 + threadIdx.x;
    int stotal = Nn * MUL0;
    if (i < stotal) {
        int n = i >> 6, j = i & 63;
        const float* ar = agg_s + (size_t)n * MIDS;
        float a1 = 0.f, a2 = 0.f;
        #pragma unroll
        for (int u = 0; u < MUL0; u++)
            a1 = fmaf(ldf<BF>(ns, (size_t)n * MUL0 + u), Wscs[u * MUL0 + j], a1);
        #pragma unroll
        for (int u = 0; u < MIDS; u++) a2 = fmaf(ar[u], Wl2s[u * MUL0 + j], a2);
        float o = ldf<BF>(attr, n) * (cosb[n] * a1 + sinb[n] * a2);
        stf<BF>(out, (size_t)n * 160 + j, o);
    } else {
        int m = i - stotal;
        if (m >= Nn * 96) return;
        int n = m / 96; int idx = m - n * 96;
        int vi = idx / 3; int c = idx - vi * 3;
        const float* ar = agg_v + (size_t)n * (MIDV * 3);
        float a1 = 0.f, a2 = 0.f;
        #pragma unroll
        for (int u = 0; u < MUL1; u++)
            a1 = fmaf(ldf<BF>(nv, (size_t)n * 96 + u * 3 + c), Wscv[u * MUL1 + vi], a1);
        #pragma unroll
        for (int u = 0; u < MIDV; u++) a2 = fmaf(ar[u * 3 + c], Wl2v[u * MUL1 + vi], a2);
        float o = ldf<BF>(attr, n) * (cosb[n] * a1 + sinb[n] * a2);
        stf<BF>(out, (size_t)n * 160 + 64 + idx, o);
    }
}
__global__ __launch_bounds__(256) void k_final(
    const void* ns, const void* nv, const void* attr,
    const float* Wscs, const float* Wscv,
    const float* Wl2s, const float* Wl2v,
    const float* agg_s, const float* agg_v,
    const float* cosb, const float* sinb,
    void* out, int Nn, const int* flag)
{
    if (*flag) final_body<true >(ns, nv, attr, Wscs, Wscv, Wl2s, Wl2v, agg_s, agg_v, cosb, sinb, out, Nn);
    else       final_body<false>(ns, nv, attr, Wscs, Wscv, Wl2s, Wl2v, agg_s, agg_v, cosb, sinb, out, Nn);
}

// ---------------- launch ----------------
extern "C" void kernel_launch(void* const* d_in, const int* in_sizes, int n_in,
                              void* d_out, int out_size, void* d_ws, size_t ws_size,
                              hipStream_t stream)
{
    const void* ns    = d_in[0];
    const void* nv    = d_in[1];
    const void* attr  = d_in[2];
    const int*  esrc  = (const int*)d_in[3];
    const int*  edst  = (const int*)d_in[4];
    const void* eattr = d_in[5];
    const void* escal = d_in[6];

    const int Nn   = in_sizes[2];   // node_attr is (N,1)
    const int Ecnt = in_sizes[3];   // edge_src is (E,)

    float* ws = (float*)d_ws;
    int* flag = (int*)(ws + OFF_FLAG);
    const size_t OFF_FS   = OFF_DYN;
    const size_t OFF_FV   = OFF_FS   + (size_t)Nn * 64;
    const size_t OFF_AGGS = OFF_FV   + (size_t)Nn * 96;
    const size_t OFF_AGGV = OFF_AGGS + (size_t)Nn * 96;
    const size_t OFF_COS  = OFF_AGGV + (size_t)Nn * 384;
    const size_t OFF_SIN  = OFF_COS  + (size_t)Nn;
    const size_t OFF_CNT  = OFF_SIN  + (size_t)Nn;       // int[Nn]
    const size_t OFF_ROW  = OFF_CNT  + (size_t)Nn;       // int[Nn+1]
    const size_t OFF_CUR  = OFF_ROW  + (size_t)Nn + 1;   // int[Nn]
    const size_t OFF_PERM = OFF_CUR  + (size_t)Nn;       // int[Ecnt]

    int* cnt       = (int*)(ws + OFF_CNT);
    int* row_start = (int*)(ws + OFF_ROW);
    int* cur       = (int*)(ws + OFF_CUR);
    int* perm      = (int*)(ws + OFF_PERM);

    k_probe<<<1, 64, 0, stream>>>((const unsigned int*)attr, flag);

    k_convert<<<(OFF_WEND + 255) / 256, 256, 0, stream>>>(
        d_in[7], d_in[8], d_in[9], d_in[10], d_in[11], d_in[12],
        d_in[13], d_in[14], d_in[15], ws, flag);

    // CSR by dst
    hipMemsetAsync(cnt, 0, (size_t)Nn * sizeof(int), stream);
    k_hist<<<(Ecnt + 255) / 256, 256, 0, stream>>>(edst, cnt, Ecnt);
    k_scan<<<1, 1024, 0, stream>>>(cnt, row_start, cur, Nn);
    k_place<<<(Ecnt + 255) / 256, 256, 0, stream>>>(edst, row_start, cur, perm, Ecnt);

    k_node_pre<<<((Nn * 160) + 255) / 256, 256, 0, stream>>>(
        ns, nv, attr, ws + OFF_WL1S, ws + OFF_WL1V,
        ws + OFF_FS, ws + OFF_FV, Nn, flag);

    k_edge_agg<<<(Nn + GNODES - 1) / GNODES, 256, 0, stream>>>(
        escal, eattr, attr, esrc, edst, row_start, perm,
        ws + OFF_W1, ws + OFF_W2, ws + OFF_WL3,
        ws + OFF_FS, ws + OFF_FV,
        ws + OFF_AGGS, ws + OFF_AGGV, ws + OFF_COS, ws + OFF_SIN, Nn, flag);

    k_final<<<((Nn * 160) + 255) / 256, 256, 0, stream>>>(
        ns, nv, attr,
        ws + OFF_WSCS, ws + OFF_WSCV, ws + OFF_WL2S, ws + OFF_WL2V,
        ws + OFF_AGGS, ws + OFF_AGGV, ws + OFF_COS, ws + OFF_SIN,
        (void*)d_out, Nn, flag);
}

// Round 5
// 1366.919 us; speedup vs baseline: 2.4399x; 2.4399x over previous
//
#include <hip/hip_runtime.h>

// ---------------- problem constants ----------------
#define MUL0 64
#define MUL1 32
#define NBASIS 10
#define FCH 100
#define WNUMEL 224   // 2*MUL0 + 3*MUL1
#define MIDS 96      // MUL0 + MUL1
#define MIDV 128     // MUL0 + 2*MUL1
#define EG 4         // dst nodes per workgroup in k_edge_mfma

// weight table offsets inside ws (floats), in d_in[7..15] order
#define OFF_W1   0        // W_fc1  10x100  (1000)
#define OFF_W2   1000     // W_fc2  100x224 (22400)
#define OFF_WSCS 23400    // W_sc_s 64x64   (4096)
#define OFF_WSCV 27496    // W_sc_v 32x32   (1024)
#define OFF_WL1S 28520    // W_l1_s 64x64   (4096)
#define OFF_WL1V 32616    // W_l1_v 32x32   (1024)
#define OFF_WL2S 33640    // W_l2_s 96x64   (6144)
#define OFF_WL2V 39784    // W_l2_v 128x32  (4096)
#define OFF_WL3  43880    // W_l3   96x1    (96)
#define OFF_WEND 43976
#define OFF_FLAG 43980    // dtype flag (int)
#define OFF_W1FRAG 44032  // bf16 frag layout, 3584 ushorts = 1792 floats
#define OFF_W2FRAG 45824  // bf16 frag layout, 28672 ushorts = 14336 floats
#define OFF_DYN  60160    // start of per-node buffers

typedef __attribute__((ext_vector_type(8))) short short8;
typedef __attribute__((ext_vector_type(4))) float f32x4;

// ---------------- helpers ----------------
__device__ __forceinline__ float bf2f(unsigned short h) {
    unsigned int u = ((unsigned int)h) << 16;
    float f; __builtin_memcpy(&f, &u, 4); return f;
}
__device__ __forceinline__ unsigned short f2bf(float f) {
    unsigned int u; __builtin_memcpy(&u, &f, 4);
    u += 0x7fffu + ((u >> 16) & 1u);   // round-to-nearest-even
    return (unsigned short)(u >> 16);
}
__device__ __forceinline__ float fast_silu(float x) {
    return x * __builtin_amdgcn_rcpf(1.0f + __expf(-x));
}
template<bool BF>
__device__ __forceinline__ float ldf(const void* p, size_t i) {
    if constexpr (BF) return bf2f(((const unsigned short*)p)[i]);
    else              return ((const float*)p)[i];
}
template<bool BF>
__device__ __forceinline__ void stf(void* p, size_t i, float v) {
    if constexpr (BF) ((unsigned short*)p)[i] = f2bf(v);
    else              ((float*)p)[i] = v;
}

// ---------------- kernel P: dtype probe ----------------
__global__ void k_probe(const unsigned int* __restrict__ attr_bits, int* __restrict__ flag)
{
    if (blockIdx.x == 0 && threadIdx.x == 0)
        *flag = (attr_bits[0] == 0x3F803F80u) ? 1 : 0;
}

// ---------------- kernel 0: convert all weights -> fp32 in ws ----------------
__global__ __launch_bounds__(256) void k_convert(
    const void* __restrict__ a0, const void* __restrict__ a1,
    const void* __restrict__ a2, const void* __restrict__ a3,
    const void* __restrict__ a4, const void* __restrict__ a5,
    const void* __restrict__ a6, const void* __restrict__ a7,
    const void* __restrict__ a8, float* __restrict__ wsf,
    const int* __restrict__ flag)
{
    int i = blockIdx.x * 256 + threadIdx.x;
    if (i >= OFF_WEND) return;
    const void* p; int off = i;
    if      (i < OFF_W2)   { p = a0; }
    else if (i < OFF_WSCS) { p = a1; off = i - OFF_W2; }
    else if (i < OFF_WSCV) { p = a2; off = i - OFF_WSCS; }
    else if (i < OFF_WL1S) { p = a3; off = i - OFF_WSCV; }
    else if (i < OFF_WL1V) { p = a4; off = i - OFF_WL1S; }
    else if (i < OFF_WL2S) { p = a5; off = i - OFF_WL1V; }
    else if (i < OFF_WL2V) { p = a6; off = i - OFF_WL2S; }
    else if (i < OFF_WL3)  { p = a7; off = i - OFF_WL2V; }
    else                   { p = a8; off = i - OFF_WL3; }
    wsf[i] = (*flag) ? ldf<true>(p, off) : ldf<false>(p, off);
}

// ---------------- kernel 0b: build MFMA B-fragment weight layouts (bf16) ----
// w1frag[col][k]: col 0..111, k 0..31; zero outside (col<100, k<10)
// w2frag[q][n][kk]: q 0..3 (k-tile of 32), n 0..223, kk 0..31; zero for k>=100
__global__ __launch_bounds__(256) void k_fragbuild(
    const float* __restrict__ wsf,
    unsigned short* __restrict__ w1frag, unsigned short* __restrict__ w2frag)
{
    int i = blockIdx.x * 256 + threadIdx.x;
    if (i < 112 * 32) {
        int col = i >> 5, k = i & 31;
        float v = (col < FCH && k < NBASIS) ? wsf[OFF_W1 + k * FCH + col] : 0.f;
        w1frag[i] = f2bf(v);
    }
    int j = i - 112 * 32;
    if (j >= 0 && j < 4 * 224 * 32) {
        int q = j / (224 * 32); int r = j - q * 224 * 32;
        int n = r >> 5; int kk = r & 31;
        int k = q * 32 + kk;
        float v = (k < FCH) ? wsf[OFF_W2 + k * WNUMEL + n] : 0.f;
        w2frag[j] = f2bf(v);
    }
}

// ---------------- CSR build: histogram / scan / place ----------------
__global__ __launch_bounds__(256) void k_hist(
    const int* __restrict__ edst, int* __restrict__ cnt, int Ecnt)
{
    int e = blockIdx.x * 256 + threadIdx.x;
    if (e < Ecnt) atomicAdd(&cnt[edst[e]], 1);
}

__device__ __forceinline__ int wave_incl_scan(int v) {
    int lane = threadIdx.x & 63;
    #pragma unroll
    for (int d = 1; d < 64; d <<= 1) {
        int t = __shfl_up(v, d, 64);
        if (lane >= d) v += t;
    }
    return v;
}

__global__ __launch_bounds__(1024) void k_scan(
    const int* __restrict__ cnt, int* __restrict__ row_start,
    int* __restrict__ cur, int Nn)
{
    __shared__ int wsum[16];
    __shared__ int s_off, s_tot;
    int tid = threadIdx.x, lane = tid & 63, wid = tid >> 6;
    if (tid == 0) s_off = 0;
    __syncthreads();
    for (int base = 0; base < Nn; base += 1024) {
        int i = base + tid;
        int v = (i < Nn) ? cnt[i] : 0;
        int incl = wave_incl_scan(v);
        if (lane == 63) wsum[wid] = incl;
        __syncthreads();
        if (wid == 0) {
            int wv = (lane < 16) ? wsum[lane] : 0;
            int wincl = wave_incl_scan(wv);
            if (lane < 16) wsum[lane] = wincl - wv;
            if (lane == 15) s_tot = wincl;
        }
        __syncthreads();
        int excl = s_off + wsum[wid] + incl - v;
        if (i < Nn) { row_start[i] = excl; cur[i] = 0; }
        __syncthreads();
        if (tid == 0) s_off += s_tot;
        __syncthreads();
    }
    if (threadIdx.x == 0) row_start[Nn] = s_off;
}

__global__ __launch_bounds__(256) void k_place(
    const int* __restrict__ edst, const int* __restrict__ row_start,
    int* __restrict__ cur, int* __restrict__ perm, int Ecnt)
{
    int e = blockIdx.x * 256 + threadIdx.x;
    if (e < Ecnt) {
        int d = edst[e];
        int pos = row_start[d] + atomicAdd(&cur[d], 1);
        perm[pos] = e;
    }
}

// ---------------- kernel 1: node precompute f_s, f_v ----------------
template<bool BF>
__device__ __forceinline__ void node_pre_body(
    const void* __restrict__ ns, const void* __restrict__ nv,
    const void* __restrict__ attr,
    const float* __restrict__ Wl1s, const float* __restrict__ Wl1v,
    float* __restrict__ f_s, float* __restrict__ f_v, int Nn)
{
    int i = blockIdx.x * 256 + threadIdx.x;
    int stotal = Nn * MUL0;
    if (i < stotal) {
        int n = i >> 6, j = i & 63;
        float a = 0.f;
        #pragma unroll
        for (int u = 0; u < MUL0; u++)
            a = fmaf(ldf<BF>(ns, (size_t)n * MUL0 + u), Wl1s[u * MUL0 + j], a);
        f_s[i] = a * ldf<BF>(attr, n);
    } else {
        int m = i - stotal;
        if (m >= Nn * MUL1 * 3) return;
        int n = m / 96; int idx = m - n * 96;
        int vi = idx / 3; int c = idx - vi * 3;
        float a = 0.f;
        #pragma unroll
        for (int u = 0; u < MUL1; u++)
            a = fmaf(ldf<BF>(nv, (size_t)n * 96 + u * 3 + c), Wl1v[u * MUL1 + vi], a);
        f_v[m] = a * ldf<BF>(attr, n);
    }
}
__global__ __launch_bounds__(256) void k_node_pre(
    const void* ns, const void* nv, const void* attr,
    const float* Wl1s, const float* Wl1v,
    float* f_s, float* f_v, int Nn, const int* flag)
{
    if (*flag) node_pre_body<true >(ns, nv, attr, Wl1s, Wl1v, f_s, f_v, Nn);
    else       node_pre_body<false>(ns, nv, attr, Wl1s, Wl1v, f_s, f_v, Nn);
}

// ---------------- kernel 2: MFMA edge kernel, atomic-free aggregation ------
// wg owns EG=4 consecutive dsts (CSR-contiguous edge slice). Per 64-edge tile:
//   stage es/y/src -> FC1 (mfma 16x16x32 bf16, K zero-padded) -> silu -> h_lds
//   -> FC2 (14 col-tiles x 4 ksteps) -> w_lds (bf16)
//   -> aggregation: thread owns 8 fixed (dst,feat) slots, register-accumulates
//      over that dst's CSR range (NO atomics); fs/fv reads wave-coalesced.
#define ES_STRIDE 40    // 32 + pad (bank stagger)
#define H_STRIDE 136    // 128 + pad
#define WL_STRIDE 228   // 224 + pad

__global__ __launch_bounds__(256) void k_edge_mfma(
    const void* __restrict__ escal, const void* __restrict__ eattr,
    const int* __restrict__ esrc,
    const int* __restrict__ row_start, const int* __restrict__ perm,
    const unsigned short* __restrict__ w1frag, const unsigned short* __restrict__ w2frag,
    const float* __restrict__ f_s, const float* __restrict__ f_v,
    float* __restrict__ agg_s, float* __restrict__ agg_v,
    int Nn, const int* __restrict__ flag)
{
    __shared__ __align__(16) unsigned short es_lds[64 * ES_STRIDE]; // 5 KB
    __shared__ __align__(16) unsigned short h_lds[64 * H_STRIDE];   // 17 KB
    __shared__ __align__(16) unsigned short w_lds[64 * WL_STRIDE];  // 28.5 KB
    __shared__ float y_lds[64][4];                                  // 1 KB
    __shared__ int   src_lds[64];

    const int tid  = threadIdx.x;
    const int lane = tid & 63;
    const int wave = tid >> 6;
    const int nl   = lane & 15;
    const int quad = lane >> 4;
    const int gbase = blockIdx.x * EG;
    const bool isbf = (*flag != 0);

    // one-time zero padding: es k=10..31 (A-frag K range), h k=112..127
    for (int i = tid; i < 64 * 22; i += 256) {
        int row = i / 22, k = 10 + (i - row * 22);
        es_lds[row * ES_STRIDE + k] = 0;
    }
    for (int i = tid; i < 64 * 16; i += 256) {
        int row = i >> 4, k = 112 + (i & 15);
        h_lds[row * H_STRIDE + k] = 0;
    }

    // per-slot setup: slot = tid + s*256 -> (dst d, feat f); bounds cached
    float acc[8];
    int lo0[8], hi0[8], colv[8], cse[8], uu[8], cc[8];
    #pragma unroll
    for (int s = 0; s < 8; s++) {
        acc[s] = 0.f;
        int slot = tid + s * 256;
        int d = slot / 480, f = slot - d * 480;
        int node = gbase + d;
        bool valid = (slot < EG * 480) && (node < Nn);
        lo0[s] = valid ? row_start[node] : 0;
        hi0[s] = valid ? row_start[node + 1] : 0;
        if (f < 64)       { cse[s] = 0; colv[s] = f;            uu[s] = f;      cc[s] = 0; }
        else if (f < 96)  { cse[s] = 1; colv[s] = 160 + (f-64); uu[s] = f - 64; cc[s] = 0; }
        else if (f < 288) { int p = f - 96;  int u = p / 3; cse[s] = 2; colv[s] = 64 + u;  uu[s] = u; cc[s] = p - 3*u; }
        else if (f < 384) { int p = f - 288; int u = p / 3; cse[s] = 3; colv[s] = 128 + u; uu[s] = u; cc[s] = p - 3*u; }
        else              { int p = f - 384; int u = p / 3; cse[s] = 4; colv[s] = 192 + u; uu[s] = u; cc[s] = p - 3*u; }
    }

    const int gend    = (gbase + EG < Nn) ? (gbase + EG) : Nn;
    const int e_start = row_start[gbase];
    const int e_end   = row_start[gend];

    for (int tb = e_start; tb < e_end; tb += 64) {
        const int tcnt = (e_end - tb < 64) ? (e_end - tb) : 64;
        __syncthreads();   // previous tile's aggregation done before LDS reuse

        // ---- stage per-edge front: es (bf16 pairs), y, src ----
        {
            int i = tid & 63, part = tid >> 6;
            if (i < tcnt && part < 2) {
                int e = perm[tb + i];
                if (part == 0) {
                    unsigned int* dstp = (unsigned int*)&es_lds[i * ES_STRIDE];
                    if (isbf) {
                        const unsigned int* srcp =
                            (const unsigned int*)((const unsigned short*)escal + (size_t)e * NBASIS);
                        #pragma unroll
                        for (int t2 = 0; t2 < 5; t2++) dstp[t2] = srcp[t2];
                    } else {
                        const float* srcp = (const float*)escal + (size_t)e * NBASIS;
                        #pragma unroll
                        for (int t2 = 0; t2 < 5; t2++) {
                            unsigned int lo = f2bf(srcp[2 * t2]);
                            unsigned int hi = f2bf(srcp[2 * t2 + 1]);
                            dstp[t2] = lo | (hi << 16);
                        }
                    }
                } else {
                    src_lds[i] = esrc[e];
                    if (isbf) {
                        const unsigned short* ap = (const unsigned short*)eattr + (size_t)e * 4;
                        #pragma unroll
                        for (int t2 = 0; t2 < 4; t2++) y_lds[i][t2] = bf2f(ap[t2]);
                    } else {
                        const float* ap = (const float*)eattr + (size_t)e * 4;
                        #pragma unroll
                        for (int t2 = 0; t2 < 4; t2++) y_lds[i][t2] = ap[t2];
                    }
                }
            }
        }
        __syncthreads();

        // ---- FC1: wave handles edges 16w..16w+15; 7 col-tiles, 1 kstep ----
        {
            short8 a = *(const short8*)&es_lds[(16 * wave + nl) * ES_STRIDE + quad * 8];
            f32x4 hacc[7];
            #pragma unroll
            for (int t = 0; t < 7; t++) {
                short8 b = *(const short8*)&w1frag[(16 * t + nl) * 32 + quad * 8];
                hacc[t] = __builtin_amdgcn_mfma_f32_16x16x32_bf16(
                    a, b, (f32x4){0.f, 0.f, 0.f, 0.f}, 0, 0, 0);
            }
            #pragma unroll
            for (int t = 0; t < 7; t++) {
                #pragma unroll
                for (int r = 0; r < 4; r++)
                    h_lds[(16 * wave + quad * 4 + r) * H_STRIDE + 16 * t + nl] =
                        f2bf(fast_silu(hacc[t][r]));
            }
        }
        __syncthreads();

        // ---- FC2: 14 col-tiles x 4 ksteps ----
        #pragma unroll 2
        for (int t = 0; t < 14; t++) {
            f32x4 c = {0.f, 0.f, 0.f, 0.f};
            #pragma unroll
            for (int q = 0; q < 4; q++) {
                short8 a = *(const short8*)&h_lds[(16 * wave + nl) * H_STRIDE + q * 32 + quad * 8];
                short8 b = *(const short8*)&w2frag[((q * 224) + 16 * t + nl) * 32 + quad * 8];
                c = __builtin_amdgcn_mfma_f32_16x16x32_bf16(a, b, c, 0, 0, 0);
            }
            #pragma unroll
            for (int r = 0; r < 4; r++)
                w_lds[(16 * wave + quad * 4 + r) * WL_STRIDE + 16 * t + nl] = f2bf(c[r]);
        }
        __syncthreads();

        // ---- aggregation: register accumulate over this dst's edges in tile ----
        #pragma unroll
        for (int s = 0; s < 8; s++) {
            int lo = lo0[s] > tb ? lo0[s] : tb;
            int hi = hi0[s] < tb + tcnt ? hi0[s] : tb + tcnt;
            float a2 = acc[s];
            for (int idx = lo; idx < hi; idx++) {
                int i = idx - tb;
                float wv = bf2f(w_lds[i * WL_STRIDE + colv[s]]);
                int srcn = src_lds[i];
                float m;
                if (cse[s] == 0)
                    m = wv * f_s[(size_t)srcn * 64 + uu[s]] * y_lds[i][0] * 0.25f;
                else if (cse[s] == 1) {
                    const float* vp = &f_v[(size_t)srcn * 96 + uu[s] * 3];
                    m = wv * (vp[0] * y_lds[i][1] + vp[1] * y_lds[i][2] + vp[2] * y_lds[i][3])
                           * (0.25f * 0.57735026918962576451f);
                }
                else if (cse[s] == 2)
                    m = wv * f_s[(size_t)srcn * 64 + uu[s]] * 0.25f * y_lds[i][1 + cc[s]];
                else if (cse[s] == 3)
                    m = wv * 0.25f * y_lds[i][0] * f_v[(size_t)srcn * 96 + uu[s] * 3 + cc[s]];
                else {
                    const float* vp = &f_v[(size_t)srcn * 96 + uu[s] * 3];
                    float y1x = y_lds[i][1], y1y = y_lds[i][2], y1z = y_lds[i][3];
                    float cr = (cc[s] == 0) ? (vp[1] * y1z - vp[2] * y1y)
                             : (cc[s] == 1) ? (vp[2] * y1x - vp[0] * y1z)
                                            : (vp[0] * y1y - vp[1] * y1x);
                    m = wv * cr * (0.25f * 0.70710678118654752440f);
                }
                a2 += m;
            }
            acc[s] = a2;
        }
    }

    // ---- writeback (each (dst,feat) owned by exactly one thread) ----
    #pragma unroll
    for (int s = 0; s < 8; s++) {
        int slot = tid + s * 256;
        if (slot >= EG * 480) continue;
        int d = slot / 480, f = slot - d * 480;
        int node = gbase + d;
        if (node >= Nn) continue;
        if (f < 96) agg_s[(size_t)node * MIDS + f] = acc[s];
        else        agg_v[(size_t)node * (MIDV * 3) + (f - 96)] = acc[s];
    }
}

// ---------------- kernel 3: angle -> cos/sin per node ----------------
__global__ __launch_bounds__(256) void k_angle(
    const float* __restrict__ agg_s, const float* __restrict__ Wl3,
    const void* __restrict__ attr,
    float* __restrict__ cosb, float* __restrict__ sinb, int Nn,
    const int* __restrict__ flag)
{
    int n = blockIdx.x * 256 + threadIdx.x;
    if (n >= Nn) return;
    const float* r = agg_s + (size_t)n * MIDS;
    float a = 0.f;
    #pragma unroll
    for (int u = 0; u < MIDS; u++) a = fmaf(r[u], Wl3[u], a);
    float at = (*flag) ? ldf<true>(attr, n) : ldf<false>(attr, n);
    a = 0.1f * a * at;
    cosb[n] = __cosf(a);
    sinb[n] = __sinf(a);
}

// ---------------- kernel 4: final output ----------------
template<bool BF>
__device__ __forceinline__ void final_body(
    const void* __restrict__ ns, const void* __restrict__ nv,
    const void* __restrict__ attr,
    const float* __restrict__ Wscs, const float* __restrict__ Wscv,
    const float* __restrict__ Wl2s, const float* __restrict__ Wl2v,
    const float* __restrict__ agg_s, const float* __restrict__ agg_v,
    const float* __restrict__ cosb, const float* __restrict__ sinb,
    void* __restrict__ out, int Nn)
{
    int i = blockIdx.x * 256 + threadIdx.x;
    int stotal = Nn * MUL0;
    if (i < stotal) {
        int n = i >> 6, j = i & 63;
        const float* ar = agg_s + (size_t)n * MIDS;
        float a1 = 0.f, a2 = 0.f;
        #pragma unroll
        for (int u = 0; u < MUL0; u++)
            a1 = fmaf(ldf<BF>(ns, (size_t)n * MUL0 + u), Wscs[u * MUL0 + j], a1);
        #pragma unroll
        for (int u = 0; u < MIDS; u++) a2 = fmaf(ar[u], Wl2s[u * MUL0 + j], a2);
        float o = ldf<BF>(attr, n) * (cosb[n] * a1 + sinb[n] * a2);
        stf<BF>(out, (size_t)n * 160 + j, o);
    } else {
        int m = i - stotal;
        if (m >= Nn * 96) return;
        int n = m / 96; int idx = m - n * 96;
        int vi = idx / 3; int c = idx - vi * 3;
        const float* ar = agg_v + (size_t)n * (MIDV * 3);
        float a1 = 0.f, a2 = 0.f;
        #pragma unroll
        for (int u = 0; u < MUL1; u++)
            a1 = fmaf(ldf<BF>(nv, (size_t)n * 96 + u * 3 + c), Wscv[u * MUL1 + vi], a1);
        #pragma unroll
        for (int u = 0; u < MIDV; u++) a2 = fmaf(ar[u * 3 + c], Wl2v[u * MUL1 + vi], a2);
        float o = ldf<BF>(attr, n) * (cosb[n] * a1 + sinb[n] * a2);
        stf<BF>(out, (size_t)n * 160 + 64 + idx, o);
    }
}
__global__ __launch_bounds__(256) void k_final(
    const void* ns, const void* nv, const void* attr,
    const float* Wscs, const float* Wscv,
    const float* Wl2s, const float* Wl2v,
    const float* agg_s, const float* agg_v,
    const float* cosb, const float* sinb,
    void* out, int Nn, const int* flag)
{
    if (*flag) final_body<true >(ns, nv, attr, Wscs, Wscv, Wl2s, Wl2v, agg_s, agg_v, cosb, sinb, out, Nn);
    else       final_body<false>(ns, nv, attr, Wscs, Wscv, Wl2s, Wl2v, agg_s, agg_v, cosb, sinb, out, Nn);
}

// ---------------- launch ----------------
extern "C" void kernel_launch(void* const* d_in, const int* in_sizes, int n_in,
                              void* d_out, int out_size, void* d_ws, size_t ws_size,
                              hipStream_t stream)
{
    const void* ns    = d_in[0];
    const void* nv    = d_in[1];
    const void* attr  = d_in[2];
    const int*  esrc  = (const int*)d_in[3];
    const int*  edst  = (const int*)d_in[4];
    const void* eattr = d_in[5];
    const void* escal = d_in[6];

    const int Nn   = in_sizes[2];   // node_attr is (N,1)
    const int Ecnt = in_sizes[3];   // edge_src is (E,)

    float* ws = (float*)d_ws;
    int* flag = (int*)(ws + OFF_FLAG);
    unsigned short* w1frag = (unsigned short*)(ws + OFF_W1FRAG);
    unsigned short* w2frag = (unsigned short*)(ws + OFF_W2FRAG);

    const size_t OFF_FS   = OFF_DYN;
    const size_t OFF_FV   = OFF_FS   + (size_t)Nn * 64;
    const size_t OFF_AGGS = OFF_FV   + (size_t)Nn * 96;
    const size_t OFF_AGGV = OFF_AGGS + (size_t)Nn * 96;
    const size_t OFF_COS  = OFF_AGGV + (size_t)Nn * 384;
    const size_t OFF_SIN  = OFF_COS  + (size_t)Nn;
    const size_t OFF_CNT  = OFF_SIN  + (size_t)Nn;       // int[Nn]
    const size_t OFF_ROW  = OFF_CNT  + (size_t)Nn;       // int[Nn+1]
    const size_t OFF_CUR  = OFF_ROW  + (size_t)Nn + 1;   // int[Nn]
    const size_t OFF_PERM = OFF_CUR  + (size_t)Nn;       // int[Ecnt]

    int* cnt       = (int*)(ws + OFF_CNT);
    int* row_start = (int*)(ws + OFF_ROW);
    int* cur       = (int*)(ws + OFF_CUR);
    int* perm      = (int*)(ws + OFF_PERM);

    k_probe<<<1, 64, 0, stream>>>((const unsigned int*)attr, flag);

    k_convert<<<(OFF_WEND + 255) / 256, 256, 0, stream>>>(
        d_in[7], d_in[8], d_in[9], d_in[10], d_in[11], d_in[12],
        d_in[13], d_in[14], d_in[15], ws, flag);

    k_fragbuild<<<(112 * 32 + 4 * 224 * 32 + 255) / 256, 256, 0, stream>>>(
        ws, w1frag, w2frag);

    // CSR by dst
    hipMemsetAsync(cnt, 0, (size_t)Nn * sizeof(int), stream);
    k_hist<<<(Ecnt + 255) / 256, 256, 0, stream>>>(edst, cnt, Ecnt);
    k_scan<<<1, 1024, 0, stream>>>(cnt, row_start, cur, Nn);
    k_place<<<(Ecnt + 255) / 256, 256, 0, stream>>>(edst, row_start, cur, perm, Ecnt);

    k_node_pre<<<((Nn * 160) + 255) / 256, 256, 0, stream>>>(
        ns, nv, attr, ws + OFF_WL1S, ws + OFF_WL1V,
        ws + OFF_FS, ws + OFF_FV, Nn, flag);

    k_edge_mfma<<<(Nn + EG - 1) / EG, 256, 0, stream>>>(
        escal, eattr, esrc, row_start, perm, w1frag, w2frag,
        ws + OFF_FS, ws + OFF_FV,
        ws + OFF_AGGS, ws + OFF_AGGV, Nn, flag);

    k_angle<<<(Nn + 255) / 256, 256, 0, stream>>>(
        ws + OFF_AGGS, ws + OFF_WL3, attr,
        ws + OFF_COS, ws + OFF_SIN, Nn, flag);

    k_final<<<((Nn * 160) + 255) / 256, 256, 0, stream>>>(
        ns, nv, attr,
        ws + OFF_WSCS, ws + OFF_WSCV, ws + OFF_WL2S, ws + OFF_WL2V,
        ws + OFF_AGGS, ws + OFF_AGGV, ws + OFF_COS, ws + OFF_SIN,
        (void*)d_out, Nn, flag);
}

// Round 7
// 646.905 us; speedup vs baseline: 5.1555x; 2.1130x over previous
//
#include <hip/hip_runtime.h>

// ---------------- problem constants ----------------
#define MUL0 64
#define MUL1 32
#define NBASIS 10
#define FCH 100
#define WNUMEL 224   // 2*MUL0 + 3*MUL1
#define MIDS 96      // MUL0 + MUL1
#define MIDV 128     // MUL0 + 2*MUL1
#define EG 4         // dst nodes per workgroup (one per wave) in k_edge_mfma

// weight table offsets inside ws (floats), in d_in[7..15] order
#define OFF_W1   0        // W_fc1  10x100  (1000)
#define OFF_W2   1000     // W_fc2  100x224 (22400)
#define OFF_WSCS 23400    // W_sc_s 64x64   (4096)
#define OFF_WSCV 27496    // W_sc_v 32x32   (1024)
#define OFF_WL1S 28520    // W_l1_s 64x64   (4096)
#define OFF_WL1V 32616    // W_l1_v 32x32   (1024)
#define OFF_WL2S 33640    // W_l2_s 96x64   (6144)
#define OFF_WL2V 39784    // W_l2_v 128x32  (4096)
#define OFF_WL3  43880    // W_l3   96x1    (96)
#define OFF_WEND 43976
#define OFF_FLAG 43980    // dtype flag (int)
#define OFF_W1FRAG 44032  // bf16 frag layout, 3584 ushorts = 1792 floats
#define OFF_W2FRAG 45824  // bf16 frag layout, 28672 ushorts = 14336 floats
#define OFF_DYN  60160    // start of per-node buffers

typedef __attribute__((ext_vector_type(8))) short short8;
typedef __attribute__((ext_vector_type(4))) float f32x4;

// ---------------- helpers ----------------
__device__ __forceinline__ float bf2f(unsigned short h) {
    unsigned int u = ((unsigned int)h) << 16;
    float f; __builtin_memcpy(&f, &u, 4); return f;
}
__device__ __forceinline__ unsigned short f2bf(float f) {
    unsigned int u; __builtin_memcpy(&u, &f, 4);
    u += 0x7fffu + ((u >> 16) & 1u);   // round-to-nearest-even
    return (unsigned short)(u >> 16);
}
__device__ __forceinline__ float fast_silu(float x) {
    return x * __builtin_amdgcn_rcpf(1.0f + __expf(-x));
}
template<bool BF>
__device__ __forceinline__ float ldf(const void* p, size_t i) {
    if constexpr (BF) return bf2f(((const unsigned short*)p)[i]);
    else              return ((const float*)p)[i];
}
template<bool BF>
__device__ __forceinline__ void stf(void* p, size_t i, float v) {
    if constexpr (BF) ((unsigned short*)p)[i] = f2bf(v);
    else              ((float*)p)[i] = v;
}

// ---------------- kernel P: dtype probe ----------------
__global__ void k_probe(const unsigned int* __restrict__ attr_bits, int* __restrict__ flag)
{
    if (blockIdx.x == 0 && threadIdx.x == 0)
        *flag = (attr_bits[0] == 0x3F803F80u) ? 1 : 0;
}

// ---------------- kernel 0: convert all weights -> fp32 in ws ----------------
__global__ __launch_bounds__(256) void k_convert(
    const void* __restrict__ a0, const void* __restrict__ a1,
    const void* __restrict__ a2, const void* __restrict__ a3,
    const void* __restrict__ a4, const void* __restrict__ a5,
    const void* __restrict__ a6, const void* __restrict__ a7,
    const void* __restrict__ a8, float* __restrict__ wsf,
    const int* __restrict__ flag)
{
    int i = blockIdx.x * 256 + threadIdx.x;
    if (i >= OFF_WEND) return;
    const void* p; int off = i;
    if      (i < OFF_W2)   { p = a0; }
    else if (i < OFF_WSCS) { p = a1; off = i - OFF_W2; }
    else if (i < OFF_WSCV) { p = a2; off = i - OFF_WSCS; }
    else if (i < OFF_WL1S) { p = a3; off = i - OFF_WSCV; }
    else if (i < OFF_WL1V) { p = a4; off = i - OFF_WL1S; }
    else if (i < OFF_WL2S) { p = a5; off = i - OFF_WL1V; }
    else if (i < OFF_WL2V) { p = a6; off = i - OFF_WL2S; }
    else if (i < OFF_WL3)  { p = a7; off = i - OFF_WL2V; }
    else                   { p = a8; off = i - OFF_WL3; }
    wsf[i] = (*flag) ? ldf<true>(p, off) : ldf<false>(p, off);
}

// ---------------- kernel 0b: build MFMA B-fragment weight layouts (bf16) ----
__global__ __launch_bounds__(256) void k_fragbuild(
    const float* __restrict__ wsf,
    unsigned short* __restrict__ w1frag, unsigned short* __restrict__ w2frag)
{
    int i = blockIdx.x * 256 + threadIdx.x;
    if (i < 112 * 32) {
        int col = i >> 5, k = i & 31;
        float v = (col < FCH && k < NBASIS) ? wsf[OFF_W1 + k * FCH + col] : 0.f;
        w1frag[i] = f2bf(v);
    }
    int j = i - 112 * 32;
    if (j >= 0 && j < 4 * 224 * 32) {
        int q = j / (224 * 32); int r = j - q * 224 * 32;
        int n = r >> 5; int kk = r & 31;
        int k = q * 32 + kk;
        float v = (k < FCH) ? wsf[OFF_W2 + k * WNUMEL + n] : 0.f;
        w2frag[j] = f2bf(v);
    }
}

// ---------------- CSR build: histogram / scan / place ----------------
__global__ __launch_bounds__(256) void k_hist(
    const int* __restrict__ edst, int* __restrict__ cnt, int Ecnt)
{
    int e = blockIdx.x * 256 + threadIdx.x;
    if (e < Ecnt) atomicAdd(&cnt[edst[e]], 1);
}

__device__ __forceinline__ int wave_incl_scan(int v) {
    int lane = threadIdx.x & 63;
    #pragma unroll
    for (int d = 1; d < 64; d <<= 1) {
        int t = __shfl_up(v, d, 64);
        if (lane >= d) v += t;
    }
    return v;
}

__global__ __launch_bounds__(1024) void k_scan(
    const int* __restrict__ cnt, int* __restrict__ row_start,
    int* __restrict__ cur, int Nn)
{
    __shared__ int wsum[16];
    __shared__ int s_off, s_tot;
    int tid = threadIdx.x, lane = tid & 63, wid = tid >> 6;
    if (tid == 0) s_off = 0;
    __syncthreads();
    for (int base = 0; base < Nn; base += 1024) {
        int i = base + tid;
        int v = (i < Nn) ? cnt[i] : 0;
        int incl = wave_incl_scan(v);
        if (lane == 63) wsum[wid] = incl;
        __syncthreads();
        if (wid == 0) {
            int wv = (lane < 16) ? wsum[lane] : 0;
            int wincl = wave_incl_scan(wv);
            if (lane < 16) wsum[lane] = wincl - wv;
            if (lane == 15) s_tot = wincl;
        }
        __syncthreads();
        int excl = s_off + wsum[wid] + incl - v;
        if (i < Nn) { row_start[i] = excl; cur[i] = 0; }
        __syncthreads();
        if (tid == 0) s_off += s_tot;
        __syncthreads();
    }
    if (threadIdx.x == 0) row_start[Nn] = s_off;
}

__global__ __launch_bounds__(256) void k_place(
    const int* __restrict__ edst, const int* __restrict__ row_start,
    int* __restrict__ cur, int* __restrict__ perm, int Ecnt)
{
    int e = blockIdx.x * 256 + threadIdx.x;
    if (e < Ecnt) {
        int d = edst[e];
        int pos = row_start[d] + atomicAdd(&cur[d], 1);
        perm[pos] = e;
    }
}

// ---------------- kernel 1: node precompute f_s, f_v ----------------
template<bool BF>
__device__ __forceinline__ void node_pre_body(
    const void* __restrict__ ns, const void* __restrict__ nv,
    const void* __restrict__ attr,
    const float* __restrict__ Wl1s, const float* __restrict__ Wl1v,
    float* __restrict__ f_s, float* __restrict__ f_v, int Nn)
{
    int i = blockIdx.x * 256 + threadIdx.x;
    int stotal = Nn * MUL0;
    if (i < stotal) {
        int n = i >> 6, j = i & 63;
        float a = 0.f;
        #pragma unroll
        for (int u = 0; u < MUL0; u++)
            a = fmaf(ldf<BF>(ns, (size_t)n * MUL0 + u), Wl1s[u * MUL0 + j], a);
        f_s[i] = a * ldf<BF>(attr, n);
    } else {
        int m = i - stotal;
        if (m >= Nn * MUL1 * 3) return;
        int n = m / 96; int idx = m - n * 96;
        int vi = idx / 3; int c = idx - vi * 3;
        float a = 0.f;
        #pragma unroll
        for (int u = 0; u < MUL1; u++)
            a = fmaf(ldf<BF>(nv, (size_t)n * 96 + u * 3 + c), Wl1v[u * MUL1 + vi], a);
        f_v[m] = a * ldf<BF>(attr, n);
    }
}
__global__ __launch_bounds__(256) void k_node_pre(
    const void* ns, const void* nv, const void* attr,
    const float* Wl1s, const float* Wl1v,
    float* f_s, float* f_v, int Nn, const int* flag)
{
    if (*flag) node_pre_body<true >(ns, nv, attr, Wl1s, Wl1v, f_s, f_v, Nn);
    else       node_pre_body<false>(ns, nv, attr, Wl1s, Wl1v, f_s, f_v, Nn);
}

// ---------------- kernel 2: MFMA edge kernel, slice aggregation ------------
// wg owns EG=4 consecutive dsts, ONE PER WAVE. Per 64-edge tile of the wg's
// CSR slice: stage es/y/src -> FC1 (MFMA) -> silu -> h_lds -> FC2 (MFMA) ->
// w_lds (bf16). Then wave w walks ITS dst's edges in the tile, computing all
// 480 outputs as 9 branch-free lane-slices accumulated in registers.
// ROUND-6 BUG FIX: acc[3] covers agg_v flat 64+lane (full 64 lanes) -> its
// (u,c) must derive from 64+lane, NOT 64+(lane&31) (that derivation is only
// for the half-slices s6/s8). Lanes 32..63 of segment B were corrupted.
#define ES_STRIDE 40    // 80 B rows, 16B-aligned for b128
#define H_STRIDE 136    // 272 B rows, 16B-aligned
#define WL_STRIDE 225   // scalar ushort access only; odd stride -> bank spread

__global__ __launch_bounds__(256) void k_edge_mfma(
    const void* __restrict__ escal, const void* __restrict__ eattr,
    const int* __restrict__ esrc,
    const int* __restrict__ row_start, const int* __restrict__ perm,
    const unsigned short* __restrict__ w1frag, const unsigned short* __restrict__ w2frag,
    const float* __restrict__ f_s, const float* __restrict__ f_v,
    float* __restrict__ agg_s, float* __restrict__ agg_v,
    int Nn, const int* __restrict__ flag)
{
    __shared__ __align__(16) unsigned short es_lds[64 * ES_STRIDE]; // 5 KB
    __shared__ __align__(16) unsigned short h_lds[64 * H_STRIDE];   // 17 KB
    __shared__ __align__(16) unsigned short w_lds[64 * WL_STRIDE];  // 28.1 KB
    __shared__ float y_lds[64][4];                                  // 1 KB
    __shared__ int   src_lds[64];

    const int tid  = threadIdx.x;
    const int lane = tid & 63;
    const int wave = tid >> 6;
    const int nl   = lane & 15;
    const int quad = lane >> 4;
    const int gbase = blockIdx.x * EG;
    const bool isbf = (*flag != 0);

    // one-time zero padding: es k=10..31, h k=112..127
    for (int i = tid; i < 64 * 22; i += 256) {
        int row = i / 22, k = 10 + (i - row * 22);
        es_lds[row * ES_STRIDE + k] = 0;
    }
    for (int i = tid; i < 64 * 16; i += 256) {
        int row = i >> 4, k = 112 + (i & 15);
        h_lds[row * H_STRIDE + k] = 0;
    }

    // slice constants (lane-derived, branch-free)
    const int lane2 = lane & 31;
    const int u0 = lane / 3,  c0 = lane - 3 * u0;        // p = lane       (acc2, s5, s7)
    const int pB = 64 + lane;
    const int uB = pB / 3,    cB = pB - 3 * uB;          // p = 64+lane    (acc3)  [FIXED]
    const int p2 = 128 + lane;
    const int u2 = p2 / 3,    c2 = p2 - 3 * u2;          // p = 128+lane   (acc4)
    const int pH = 64 + lane2;
    const int uH = pH / 3,    cH = pH - 3 * uH;          // p = 64+lane2   (s6, s8)
    const bool half = (lane < 32);

    // this wave's dst
    const int node = gbase + wave;
    const int dlo = (node < Nn) ? row_start[node] : 0;
    const int dhi = (node < Nn) ? row_start[node + 1] : 0;

    float acc[9];
    #pragma unroll
    for (int s = 0; s < 9; s++) acc[s] = 0.f;

    const int gend    = (gbase + EG < Nn) ? (gbase + EG) : Nn;
    const int e_start = row_start[gbase];
    const int e_end   = row_start[gend];

    for (int tb = e_start; tb < e_end; tb += 64) {
        const int tcnt = (e_end - tb < 64) ? (e_end - tb) : 64;
        __syncthreads();   // prev tile's aggregation (reads y/src/w_lds) done

        // ---- stage per-edge front: es (bf16 pairs), y, src ----
        {
            int i = tid & 63, part = tid >> 6;
            if (i < tcnt && part < 2) {
                int e = perm[tb + i];
                if (part == 0) {
                    unsigned int* dstp = (unsigned int*)&es_lds[i * ES_STRIDE];
                    if (isbf) {
                        const unsigned int* srcp =
                            (const unsigned int*)((const unsigned short*)escal + (size_t)e * NBASIS);
                        #pragma unroll
                        for (int t2 = 0; t2 < 5; t2++) dstp[t2] = srcp[t2];
                    } else {
                        const float* srcp = (const float*)escal + (size_t)e * NBASIS;
                        #pragma unroll
                        for (int t2 = 0; t2 < 5; t2++) {
                            unsigned int lo = f2bf(srcp[2 * t2]);
                            unsigned int hi = f2bf(srcp[2 * t2 + 1]);
                            dstp[t2] = lo | (hi << 16);
                        }
                    }
                } else {
                    src_lds[i] = esrc[e];
                    if (isbf) {
                        const unsigned short* ap = (const unsigned short*)eattr + (size_t)e * 4;
                        #pragma unroll
                        for (int t2 = 0; t2 < 4; t2++) y_lds[i][t2] = bf2f(ap[t2]);
                    } else {
                        const float* ap = (const float*)eattr + (size_t)e * 4;
                        #pragma unroll
                        for (int t2 = 0; t2 < 4; t2++) y_lds[i][t2] = ap[t2];
                    }
                }
            }
        }
        __syncthreads();

        // ---- FC1: wave computes h for edges 16w..16w+15 ----
        {
            short8 a = *(const short8*)&es_lds[(16 * wave + nl) * ES_STRIDE + quad * 8];
            f32x4 hacc[7];
            #pragma unroll
            for (int t = 0; t < 7; t++) {
                short8 b = *(const short8*)&w1frag[(16 * t + nl) * 32 + quad * 8];
                hacc[t] = __builtin_amdgcn_mfma_f32_16x16x32_bf16(
                    a, b, (f32x4){0.f, 0.f, 0.f, 0.f}, 0, 0, 0);
            }
            #pragma unroll
            for (int t = 0; t < 7; t++) {
                #pragma unroll
                for (int r = 0; r < 4; r++)
                    h_lds[(16 * wave + quad * 4 + r) * H_STRIDE + 16 * t + nl] =
                        f2bf(fast_silu(hacc[t][r]));
            }
        }
        __syncthreads();

        // ---- FC2: 14 col-tiles x 4 ksteps -> w_lds ----
        #pragma unroll 2
        for (int t = 0; t < 14; t++) {
            f32x4 c = {0.f, 0.f, 0.f, 0.f};
            #pragma unroll
            for (int q = 0; q < 4; q++) {
                short8 a = *(const short8*)&h_lds[(16 * wave + nl) * H_STRIDE + q * 32 + quad * 8];
                short8 b = *(const short8*)&w2frag[((q * 224) + 16 * t + nl) * 32 + quad * 8];
                c = __builtin_amdgcn_mfma_f32_16x16x32_bf16(a, b, c, 0, 0, 0);
            }
            #pragma unroll
            for (int r = 0; r < 4; r++)
                w_lds[(16 * wave + quad * 4 + r) * WL_STRIDE + 16 * t + nl] = f2bf(c[r]);
        }
        __syncthreads();

        // ---- slice aggregation: wave w walks ITS dst's edges in this tile ----
        {
            int lo = dlo > tb ? dlo : tb;
            int hi = dhi < tb + tcnt ? dhi : tb + tcnt;
            for (int idx = lo; idx < hi; idx++) {
                const int i = idx - tb;
                const int srcn = src_lds[i];
                const float y0  = y_lds[i][0];
                const float y1x = y_lds[i][1];
                const float y1y = y_lds[i][2];
                const float y1z = y_lds[i][3];
                const float* fsr = f_s + (size_t)srcn * 64;
                const float* fvr = f_v + (size_t)srcn * 96;
                const unsigned short* wrow = &w_lds[i * WL_STRIDE];

                // shared loads
                float fs_l  = fsr[lane];
                float fs_u0 = fsr[u0];
                float fs_uB = fsr[uB];
                float fs_u2 = fsr[u2];
                float fvA0 = fvr[lane2 * 3], fvA1 = fvr[lane2 * 3 + 1], fvA2 = fvr[lane2 * 3 + 2];
                float fvB0 = fvr[u0 * 3],    fvB1 = fvr[u0 * 3 + 1],    fvB2 = fvr[u0 * 3 + 2];
                float fvH0 = fvr[uH * 3],    fvH1 = fvr[uH * 3 + 1],    fvH2 = fvr[uH * 3 + 2];

                float y1c0 = (c0 == 0) ? y1x : (c0 == 1) ? y1y : y1z;
                float y1cB = (cB == 0) ? y1x : (cB == 1) ? y1y : y1z;
                float y1c2 = (c2 == 0) ? y1x : (c2 == 1) ? y1y : y1z;

                // w values (9 LDS ushorts)
                float w_s0 = bf2f(wrow[lane]);               // A  col = lane
                float w_s1 = bf2f(wrow[160 + lane2]);        // D  col = 160+u
                float w_s2 = bf2f(wrow[64 + u0]);            // B
                float w_s3 = bf2f(wrow[64 + uB]);
                float w_s4 = bf2f(wrow[64 + u2]);
                float w_s5 = bf2f(wrow[128 + u0]);           // C
                float w_s6 = bf2f(wrow[128 + uH]);
                float w_s7 = bf2f(wrow[192 + u0]);           // E
                float w_s8 = bf2f(wrow[192 + uH]);

                const float k14 = 0.25f;
                const float k13 = 0.25f * 0.57735026918962576451f;
                const float k12 = 0.25f * 0.70710678118654752440f;

                // s0: A  f=lane
                acc[0] = fmaf(w_s0 * fs_l, y0 * k14, acc[0]);
                // s1: D  f=64+lane (lane<32)
                {
                    float dot = fvA0 * y1x + fvA1 * y1y + fvA2 * y1z;
                    acc[1] = fmaf(w_s1 * dot, k13, acc[1]);
                }
                // s2..s4: B  agg_v flat {lane, 64+lane, 128+lane}
                acc[2] = fmaf(w_s2 * fs_u0, k14 * y1c0, acc[2]);
                acc[3] = fmaf(w_s3 * fs_uB, k14 * y1cB, acc[3]);
                acc[4] = fmaf(w_s4 * fs_u2, k14 * y1c2, acc[4]);
                // s5: C  flat 192+lane; s6: C flat 256+lane2 (lane<32)
                {
                    float e5 = (c0 == 0) ? fvB0 : (c0 == 1) ? fvB1 : fvB2;
                    float e6 = (cH == 0) ? fvH0 : (cH == 1) ? fvH1 : fvH2;
                    acc[5] = fmaf(w_s5 * e5, k14 * y0, acc[5]);
                    acc[6] = fmaf(w_s6 * e6, k14 * y0, acc[6]);
                }
                // s7: E  flat 288+lane; s8: E flat 352+lane2 (lane<32)
                {
                    float cr7 = (c0 == 0) ? (fvB1 * y1z - fvB2 * y1y)
                              : (c0 == 1) ? (fvB2 * y1x - fvB0 * y1z)
                                          : (fvB0 * y1y - fvB1 * y1x);
                    float cr8 = (cH == 0) ? (fvH1 * y1z - fvH2 * y1y)
                              : (cH == 1) ? (fvH2 * y1x - fvH0 * y1z)
                                          : (fvH0 * y1y - fvH1 * y1x);
                    acc[7] = fmaf(w_s7 * cr7, k12, acc[7]);
                    acc[8] = fmaf(w_s8 * cr8, k12, acc[8]);
                }
            }
        }
    }

    // ---- writeback: wave w owns dst gbase+w exclusively ----
    if (node < Nn) {
        float* as = agg_s + (size_t)node * MIDS;
        float* av = agg_v + (size_t)node * (MIDV * 3);
        as[lane] = acc[0];
        if (half) as[64 + lane] = acc[1];
        av[lane]       = acc[2];
        av[64 + lane]  = acc[3];
        av[128 + lane] = acc[4];
        av[192 + lane] = acc[5];
        if (half) av[256 + lane] = acc[6];
        av[288 + lane] = acc[7];
        if (half) av[352 + lane] = acc[8];
    }
}

// ---------------- kernel 3: angle -> cos/sin per node ----------------
__global__ __launch_bounds__(256) void k_angle(
    const float* __restrict__ agg_s, const float* __restrict__ Wl3,
    const void* __restrict__ attr,
    float* __restrict__ cosb, float* __restrict__ sinb, int Nn,
    const int* __restrict__ flag)
{
    int n = blockIdx.x * 256 + threadIdx.x;
    if (n >= Nn) return;
    const float* r = agg_s + (size_t)n * MIDS;
    float a = 0.f;
    #pragma unroll
    for (int u = 0; u < MIDS; u++) a = fmaf(r[u], Wl3[u], a);
    float at = (*flag) ? ldf<true>(attr, n) : ldf<false>(attr, n);
    a = 0.1f * a * at;
    cosb[n] = __cosf(a);
    sinb[n] = __sinf(a);
}

// ---------------- kernel 4: final output ----------------
template<bool BF>
__device__ __forceinline__ void final_body(
    const void* __restrict__ ns, const void* __restrict__ nv,
    const void* __restrict__ attr,
    const float* __restrict__ Wscs, const float* __restrict__ Wscv,
    const float* __restrict__ Wl2s, const float* __restrict__ Wl2v,
    const float* __restrict__ agg_s, const float* __restrict__ agg_v,
    const float* __restrict__ cosb, const float* __restrict__ sinb,
    void* __restrict__ out, int Nn)
{
    int i = blockIdx.x * 256 + threadIdx.x;
    int stotal = Nn * MUL0;
    if (i < stotal) {
        int n = i >> 6, j = i & 63;
        const float* ar = agg_s + (size_t)n * MIDS;
        float a1 = 0.f, a2 = 0.f;
        #pragma unroll
        for (int u = 0; u < MUL0; u++)
            a1 = fmaf(ldf<BF>(ns, (size_t)n * MUL0 + u), Wscs[u * MUL0 + j], a1);
        #pragma unroll
        for (int u = 0; u < MIDS; u++) a2 = fmaf(ar[u], Wl2s[u * MUL0 + j], a2);
        float o = ldf<BF>(attr, n) * (cosb[n] * a1 + sinb[n] * a2);
        stf<BF>(out, (size_t)n * 160 + j, o);
    } else {
        int m = i - stotal;
        if (m >= Nn * 96) return;
        int n = m / 96; int idx = m - n * 96;
        int vi = idx / 3; int c = idx - vi * 3;
        const float* ar = agg_v + (size_t)n * (MIDV * 3);
        float a1 = 0.f, a2 = 0.f;
        #pragma unroll
        for (int u = 0; u < MUL1; u++)
            a1 = fmaf(ldf<BF>(nv, (size_t)n * 96 + u * 3 + c), Wscv[u * MUL1 + vi], a1);
        #pragma unroll
        for (int u = 0; u < MIDV; u++) a2 = fmaf(ar[u * 3 + c], Wl2v[u * MUL1 + vi], a2);
        float o = ldf<BF>(attr, n) * (cosb[n] * a1 + sinb[n] * a2);
        stf<BF>(out, (size_t)n * 160 + 64 + idx, o);
    }
}
__global__ __launch_bounds__(256) void k_final(
    const void* ns, const void* nv, const void* attr,
    const float* Wscs, const float* Wscv,
    const float* Wl2s, const float* Wl2v,
    const float* agg_s, const float* agg_v,
    const float* cosb, const float* sinb,
    void* out, int Nn, const int* flag)
{
    if (*flag) final_body<true >(ns, nv, attr, Wscs, Wscv, Wl2s, Wl2v, agg_s, agg_v, cosb, sinb, out, Nn);
    else       final_body<false>(ns, nv, attr, Wscs, Wscv, Wl2s, Wl2v, agg_s, agg_v, cosb, sinb, out, Nn);
}

// ---------------- launch ----------------
extern "C" void kernel_launch(void* const* d_in, const int* in_sizes, int n_in,
                              void* d_out, int out_size, void* d_ws, size_t ws_size,
                              hipStream_t stream)
{
    const void* ns    = d_in[0];
    const void* nv    = d_in[1];
    const void* attr  = d_in[2];
    const int*  esrc  = (const int*)d_in[3];
    const int*  edst  = (const int*)d_in[4];
    const void* eattr = d_in[5];
    const void* escal = d_in[6];

    const int Nn   = in_sizes[2];   // node_attr is (N,1)
    const int Ecnt = in_sizes[3];   // edge_src is (E,)

    float* ws = (float*)d_ws;
    int* flag = (int*)(ws + OFF_FLAG);
    unsigned short* w1frag = (unsigned short*)(ws + OFF_W1FRAG);
    unsigned short* w2frag = (unsigned short*)(ws + OFF_W2FRAG);

    const size_t OFF_FS   = OFF_DYN;
    const size_t OFF_FV   = OFF_FS   + (size_t)Nn * 64;
    const size_t OFF_AGGS = OFF_FV   + (size_t)Nn * 96;
    const size_t OFF_AGGV = OFF_AGGS + (size_t)Nn * 96;
    const size_t OFF_COS  = OFF_AGGV + (size_t)Nn * 384;
    const size_t OFF_SIN  = OFF_COS  + (size_t)Nn;
    const size_t OFF_CNT  = OFF_SIN  + (size_t)Nn;       // int[Nn]
    const size_t OFF_ROW  = OFF_CNT  + (size_t)Nn;       // int[Nn+1]
    const size_t OFF_CUR  = OFF_ROW  + (size_t)Nn + 1;   // int[Nn]
    const size_t OFF_PERM = OFF_CUR  + (size_t)Nn;       // int[Ecnt]

    int* cnt       = (int*)(ws + OFF_CNT);
    int* row_start = (int*)(ws + OFF_ROW);
    int* cur       = (int*)(ws + OFF_CUR);
    int* perm      = (int*)(ws + OFF_PERM);

    k_probe<<<1, 64, 0, stream>>>((const unsigned int*)attr, flag);

    k_convert<<<(OFF_WEND + 255) / 256, 256, 0, stream>>>(
        d_in[7], d_in[8], d_in[9], d_in[10], d_in[11], d_in[12],
        d_in[13], d_in[14], d_in[15], ws, flag);

    k_fragbuild<<<(112 * 32 + 4 * 224 * 32 + 255) / 256, 256, 0, stream>>>(
        ws, w1frag, w2frag);

    // CSR by dst
    hipMemsetAsync(cnt, 0, (size_t)Nn * sizeof(int), stream);
    k_hist<<<(Ecnt + 255) / 256, 256, 0, stream>>>(edst, cnt, Ecnt);
    k_scan<<<1, 1024, 0, stream>>>(cnt, row_start, cur, Nn);
    k_place<<<(Ecnt + 255) / 256, 256, 0, stream>>>(edst, row_start, cur, perm, Ecnt);

    k_node_pre<<<((Nn * 160) + 255) / 256, 256, 0, stream>>>(
        ns, nv, attr, ws + OFF_WL1S, ws + OFF_WL1V,
        ws + OFF_FS, ws + OFF_FV, Nn, flag);

    k_edge_mfma<<<(Nn + EG - 1) / EG, 256, 0, stream>>>(
        escal, eattr, esrc, row_start, perm, w1frag, w2frag,
        ws + OFF_FS, ws + OFF_FV,
        ws + OFF_AGGS, ws + OFF_AGGV, Nn, flag);

    k_angle<<<(Nn + 255) / 256, 256, 0, stream>>>(
        ws + OFF_AGGS, ws + OFF_WL3, attr,
        ws + OFF_COS, ws + OFF_SIN, Nn, flag);

    k_final<<<((Nn * 160) + 255) / 256, 256, 0, stream>>>(
        ns, nv, attr,
        ws + OFF_WSCS, ws + OFF_WSCV, ws + OFF_WL2S, ws + OFF_WL2V,
        ws + OFF_AGGS, ws + OFF_AGGV, ws + OFF_COS, ws + OFF_SIN,
        (void*)d_out, Nn, flag);
}

// Round 8
// 641.805 us; speedup vs baseline: 5.1964x; 1.0079x over previous
//
#include <hip/hip_runtime.h>

// ---------------- problem constants ----------------
#define MUL0 64
#define MUL1 32
#define NBASIS 10
#define FCH 100
#define WNUMEL 224   // 2*MUL0 + 3*MUL1
#define MIDS 96      // MUL0 + MUL1
#define MIDV 128     // MUL0 + 2*MUL1
#define EG 4         // dst nodes per workgroup (one per wave) in k_edge_mfma

// weight table offsets inside ws (floats), in d_in[7..15] order
#define OFF_W1   0        // W_fc1  10x100  (1000)
#define OFF_W2   1000     // W_fc2  100x224 (22400)
#define OFF_WSCS 23400    // W_sc_s 64x64   (4096)
#define OFF_WSCV 27496    // W_sc_v 32x32   (1024)
#define OFF_WL1S 28520    // W_l1_s 64x64   (4096)
#define OFF_WL1V 32616    // W_l1_v 32x32   (1024)
#define OFF_WL2S 33640    // W_l2_s 96x64   (6144)
#define OFF_WL2V 39784    // W_l2_v 128x32  (4096)
#define OFF_WL3  43880    // W_l3   96x1    (96)
#define OFF_WEND 43976
#define OFF_FLAG 43980    // dtype flag (int)
#define OFF_W1FRAG 44032  // bf16 frag layout, 3584 ushorts = 1792 floats
#define OFF_W2FRAG 45824  // bf16 frag layout, 28672 ushorts = 14336 floats
#define OFF_DYN  60160    // start of per-node buffers

#define W1FRAG_N (112 * 32)       // 3584
#define W2FRAG_N (4 * 224 * 32)   // 28672

typedef __attribute__((ext_vector_type(8))) short short8;
typedef __attribute__((ext_vector_type(4))) float f32x4;

// ---------------- helpers ----------------
__device__ __forceinline__ float bf2f(unsigned short h) {
    unsigned int u = ((unsigned int)h) << 16;
    float f; __builtin_memcpy(&f, &u, 4); return f;
}
__device__ __forceinline__ unsigned short f2bf(float f) {
    unsigned int u; __builtin_memcpy(&u, &f, 4);
    u += 0x7fffu + ((u >> 16) & 1u);   // round-to-nearest-even
    return (unsigned short)(u >> 16);
}
__device__ __forceinline__ float fast_silu(float x) {
    return x * __builtin_amdgcn_rcpf(1.0f + __expf(-x));
}
template<bool BF>
__device__ __forceinline__ float ldf(const void* p, size_t i) {
    if constexpr (BF) return bf2f(((const unsigned short*)p)[i]);
    else              return ((const float*)p)[i];
}
template<bool BF>
__device__ __forceinline__ void stf(void* p, size_t i, float v) {
    if constexpr (BF) ((unsigned short*)p)[i] = f2bf(v);
    else              ((float*)p)[i] = v;
}

// ---------------- node precompute body (reads RAW inputs only) -------------
template<bool BF>
__device__ __forceinline__ void node_pre_body(
    const void* __restrict__ ns, const void* __restrict__ nv,
    const void* __restrict__ attr,
    const void* __restrict__ Wl1s, const void* __restrict__ Wl1v,
    float* __restrict__ f_s, float* __restrict__ f_v, int i, int Nn)
{
    int stotal = Nn * MUL0;
    if (i < stotal) {
        int n = i >> 6, j = i & 63;
        float a = 0.f;
        #pragma unroll
        for (int u = 0; u < MUL0; u++)
            a = fmaf(ldf<BF>(ns, (size_t)n * MUL0 + u), ldf<BF>(Wl1s, u * MUL0 + j), a);
        f_s[i] = a * ldf<BF>(attr, n);
    } else {
        int m = i - stotal;
        if (m >= Nn * MUL1 * 3) return;
        int n = m / 96; int idx = m - n * 96;
        int vi = idx / 3; int c = idx - vi * 3;
        float a = 0.f;
        #pragma unroll
        for (int u = 0; u < MUL1; u++)
            a = fmaf(ldf<BF>(nv, (size_t)n * 96 + u * 3 + c), ldf<BF>(Wl1v, u * MUL1 + vi), a);
        f_v[m] = a * ldf<BF>(attr, n);
    }
}

// ---------------- kernel PREP: fuses dtype-probe + weight convert +
// MFMA frag build + cnt zero + node precompute (all read only d_in) ---------
__global__ __launch_bounds__(256) void k_prep(
    const void* __restrict__ ns, const void* __restrict__ nv,
    const void* __restrict__ attr,
    const void* __restrict__ a0, const void* __restrict__ a1,
    const void* __restrict__ a2, const void* __restrict__ a3,
    const void* __restrict__ a4, const void* __restrict__ a5,
    const void* __restrict__ a6, const void* __restrict__ a7,
    const void* __restrict__ a8,
    float* __restrict__ wsf,
    unsigned short* __restrict__ w1frag, unsigned short* __restrict__ w2frag,
    int* __restrict__ cnt, int* __restrict__ flag,
    float* __restrict__ f_s, float* __restrict__ f_v, int Nn)
{
    const bool bf = (((const unsigned int*)attr)[0] == 0x3F803F80u);
    int i = blockIdx.x * 256 + threadIdx.x;
    if (i == 0) *flag = bf ? 1 : 0;

    const int npre = Nn * 160;
    if (i < npre) {
        if (bf) node_pre_body<true >(ns, nv, attr, a4, a5, f_s, f_v, i, Nn);
        else    node_pre_body<false>(ns, nv, attr, a4, a5, f_s, f_v, i, Nn);
        return;
    }
    int m = i - npre;
    if (m < OFF_WEND) {
        const void* p; int off = m;
        if      (m < OFF_W2)   { p = a0; }
        else if (m < OFF_WSCS) { p = a1; off = m - OFF_W2; }
        else if (m < OFF_WSCV) { p = a2; off = m - OFF_WSCS; }
        else if (m < OFF_WL1S) { p = a3; off = m - OFF_WSCV; }
        else if (m < OFF_WL1V) { p = a4; off = m - OFF_WL1S; }
        else if (m < OFF_WL2S) { p = a5; off = m - OFF_WL1V; }
        else if (m < OFF_WL2V) { p = a6; off = m - OFF_WL2S; }
        else if (m < OFF_WL3)  { p = a7; off = m - OFF_WL2V; }
        else                   { p = a8; off = m - OFF_WL3; }
        wsf[m] = bf ? ldf<true>(p, off) : ldf<false>(p, off);
        return;
    }
    m -= OFF_WEND;
    if (m < W1FRAG_N) {
        int col = m >> 5, k = m & 31;
        float v = 0.f;
        if (col < FCH && k < NBASIS)
            v = bf ? ldf<true>(a0, k * FCH + col) : ldf<false>(a0, k * FCH + col);
        w1frag[m] = f2bf(v);
        return;
    }
    m -= W1FRAG_N;
    if (m < W2FRAG_N) {
        int q = m / (224 * 32); int r = m - q * 224 * 32;
        int n = r >> 5; int kk = r & 31;
        int k = q * 32 + kk;
        float v = 0.f;
        if (k < FCH)
            v = bf ? ldf<true>(a1, k * WNUMEL + n) : ldf<false>(a1, k * WNUMEL + n);
        w2frag[m] = f2bf(v);
        return;
    }
    m -= W2FRAG_N;
    if (m < Nn) cnt[m] = 0;
}

// ---------------- CSR build: histogram / scan / place ----------------
__global__ __launch_bounds__(256) void k_hist(
    const int* __restrict__ edst, int* __restrict__ cnt, int Ecnt)
{
    int e = blockIdx.x * 256 + threadIdx.x;
    if (e < Ecnt) atomicAdd(&cnt[edst[e]], 1);
}

__device__ __forceinline__ int wave_incl_scan(int v) {
    int lane = threadIdx.x & 63;
    #pragma unroll
    for (int d = 1; d < 64; d <<= 1) {
        int t = __shfl_up(v, d, 64);
        if (lane >= d) v += t;
    }
    return v;
}

__global__ __launch_bounds__(1024) void k_scan(
    const int* __restrict__ cnt, int* __restrict__ row_start,
    int* __restrict__ cur, int Nn)
{
    __shared__ int wsum[16];
    __shared__ int s_off, s_tot;
    int tid = threadIdx.x, lane = tid & 63, wid = tid >> 6;
    if (tid == 0) s_off = 0;
    __syncthreads();
    for (int base = 0; base < Nn; base += 1024) {
        int i = base + tid;
        int v = (i < Nn) ? cnt[i] : 0;
        int incl = wave_incl_scan(v);
        if (lane == 63) wsum[wid] = incl;
        __syncthreads();
        if (wid == 0) {
            int wv = (lane < 16) ? wsum[lane] : 0;
            int wincl = wave_incl_scan(wv);
            if (lane < 16) wsum[lane] = wincl - wv;
            if (lane == 15) s_tot = wincl;
        }
        __syncthreads();
        int excl = s_off + wsum[wid] + incl - v;
        if (i < Nn) { row_start[i] = excl; cur[i] = 0; }
        __syncthreads();
        if (tid == 0) s_off += s_tot;
        __syncthreads();
    }
    if (threadIdx.x == 0) row_start[Nn] = s_off;
}

__global__ __launch_bounds__(256) void k_place(
    const int* __restrict__ edst, const int* __restrict__ row_start,
    int* __restrict__ cur, int* __restrict__ perm, int Ecnt)
{
    int e = blockIdx.x * 256 + threadIdx.x;
    if (e < Ecnt) {
        int d = edst[e];
        int pos = row_start[d] + atomicAdd(&cur[d], 1);
        perm[pos] = e;
    }
}

// ---------------- kernel 2: MFMA edge kernel, slice aggregation ------------
// wg owns EG=4 consecutive dsts, ONE PER WAVE. Per 64-edge tile of the wg's
// CSR slice: stage es/y/src -> FC1 (MFMA) -> silu -> h_lds -> FC2 (MFMA) ->
// w_lds (bf16). Then wave w walks ITS dst's edges: srcn hoisted to lane regs
// (shfl broadcast, removes the LDS-read -> global-gather serial chain) and
// unroll-4 so 4 iterations' L2 gathers are in flight. Fused angle epilogue
// (agg_s lives in acc[0]/acc[1]; shfl-butterfly dot with W_l3).
#define ES_STRIDE 40    // 80 B rows, 16B-aligned for b128
#define H_STRIDE 136    // 272 B rows, 16B-aligned
#define WL_STRIDE 225   // scalar ushort access only; odd stride -> bank spread

__global__ __launch_bounds__(256) void k_edge_mfma(
    const void* __restrict__ escal, const void* __restrict__ eattr,
    const void* __restrict__ attr,
    const int* __restrict__ esrc,
    const int* __restrict__ row_start, const int* __restrict__ perm,
    const unsigned short* __restrict__ w1frag, const unsigned short* __restrict__ w2frag,
    const float* __restrict__ Wl3,
    const float* __restrict__ f_s, const float* __restrict__ f_v,
    float* __restrict__ agg_s, float* __restrict__ agg_v,
    float* __restrict__ cosb, float* __restrict__ sinb,
    int Nn, const int* __restrict__ flag)
{
    __shared__ __align__(16) unsigned short es_lds[64 * ES_STRIDE]; // 5 KB
    __shared__ __align__(16) unsigned short h_lds[64 * H_STRIDE];   // 17 KB
    __shared__ __align__(16) unsigned short w_lds[64 * WL_STRIDE];  // 28.1 KB
    __shared__ float y_lds[64][4];                                  // 1 KB
    __shared__ int   src_lds[64];

    const int tid  = threadIdx.x;
    const int lane = tid & 63;
    const int wave = tid >> 6;
    const int nl   = lane & 15;
    const int quad = lane >> 4;
    const int gbase = blockIdx.x * EG;
    const bool isbf = (*flag != 0);

    // one-time zero padding: es k=10..31, h k=112..127
    for (int i = tid; i < 64 * 22; i += 256) {
        int row = i / 22, k = 10 + (i - row * 22);
        es_lds[row * ES_STRIDE + k] = 0;
    }
    for (int i = tid; i < 64 * 16; i += 256) {
        int row = i >> 4, k = 112 + (i & 15);
        h_lds[row * H_STRIDE + k] = 0;
    }

    // slice constants (lane-derived, branch-free)
    const int lane2 = lane & 31;
    const int u0 = lane / 3,  c0 = lane - 3 * u0;        // p = lane       (acc2, s5, s7)
    const int pB = 64 + lane;
    const int uB = pB / 3,    cB = pB - 3 * uB;          // p = 64+lane    (acc3)
    const int p2 = 128 + lane;
    const int u2 = p2 / 3,    c2 = p2 - 3 * u2;          // p = 128+lane   (acc4)
    const int pH = 64 + lane2;
    const int uH = pH / 3,    cH = pH - 3 * uH;          // p = 64+lane2   (s6, s8)
    const bool half = (lane < 32);

    // this wave's dst
    const int node = gbase + wave;
    const int dlo = (node < Nn) ? row_start[node] : 0;
    const int dhi = (node < Nn) ? row_start[node + 1] : 0;

    float acc[9];
    #pragma unroll
    for (int s = 0; s < 9; s++) acc[s] = 0.f;

    const int gend    = (gbase + EG < Nn) ? (gbase + EG) : Nn;
    const int e_start = row_start[gbase];
    const int e_end   = row_start[gend];

    for (int tb = e_start; tb < e_end; tb += 64) {
        const int tcnt = (e_end - tb < 64) ? (e_end - tb) : 64;
        __syncthreads();   // prev tile's aggregation (reads y/src/w_lds) done

        // ---- stage per-edge front: es (bf16 pairs), y, src ----
        {
            int i = tid & 63, part = tid >> 6;
            if (i < tcnt && part < 2) {
                int e = perm[tb + i];
                if (part == 0) {
                    unsigned int* dstp = (unsigned int*)&es_lds[i * ES_STRIDE];
                    if (isbf) {
                        const unsigned int* srcp =
                            (const unsigned int*)((const unsigned short*)escal + (size_t)e * NBASIS);
                        #pragma unroll
                        for (int t2 = 0; t2 < 5; t2++) dstp[t2] = srcp[t2];
                    } else {
                        const float* srcp = (const float*)escal + (size_t)e * NBASIS;
                        #pragma unroll
                        for (int t2 = 0; t2 < 5; t2++) {
                            unsigned int lo = f2bf(srcp[2 * t2]);
                            unsigned int hi = f2bf(srcp[2 * t2 + 1]);
                            dstp[t2] = lo | (hi << 16);
                        }
                    }
                } else {
                    src_lds[i] = esrc[e];
                    if (isbf) {
                        const unsigned short* ap = (const unsigned short*)eattr + (size_t)e * 4;
                        #pragma unroll
                        for (int t2 = 0; t2 < 4; t2++) y_lds[i][t2] = bf2f(ap[t2]);
                    } else {
                        const float* ap = (const float*)eattr + (size_t)e * 4;
                        #pragma unroll
                        for (int t2 = 0; t2 < 4; t2++) y_lds[i][t2] = ap[t2];
                    }
                }
            }
        }
        __syncthreads();

        // ---- FC1: wave computes h for edges 16w..16w+15 ----
        {
            short8 a = *(const short8*)&es_lds[(16 * wave + nl) * ES_STRIDE + quad * 8];
            f32x4 hacc[7];
            #pragma unroll
            for (int t = 0; t < 7; t++) {
                short8 b = *(const short8*)&w1frag[(16 * t + nl) * 32 + quad * 8];
                hacc[t] = __builtin_amdgcn_mfma_f32_16x16x32_bf16(
                    a, b, (f32x4){0.f, 0.f, 0.f, 0.f}, 0, 0, 0);
            }
            #pragma unroll
            for (int t = 0; t < 7; t++) {
                #pragma unroll
                for (int r = 0; r < 4; r++)
                    h_lds[(16 * wave + quad * 4 + r) * H_STRIDE + 16 * t + nl] =
                        f2bf(fast_silu(hacc[t][r]));
            }
        }
        __syncthreads();

        // ---- FC2: 14 col-tiles x 4 ksteps -> w_lds ----
        #pragma unroll 2
        for (int t = 0; t < 14; t++) {
            f32x4 c = {0.f, 0.f, 0.f, 0.f};
            #pragma unroll
            for (int q = 0; q < 4; q++) {
                short8 a = *(const short8*)&h_lds[(16 * wave + nl) * H_STRIDE + q * 32 + quad * 8];
                short8 b = *(const short8*)&w2frag[((q * 224) + 16 * t + nl) * 32 + quad * 8];
                c = __builtin_amdgcn_mfma_f32_16x16x32_bf16(a, b, c, 0, 0, 0);
            }
            #pragma unroll
            for (int r = 0; r < 4; r++)
                w_lds[(16 * wave + quad * 4 + r) * WL_STRIDE + 16 * t + nl] = f2bf(c[r]);
        }
        __syncthreads();

        // ---- slice aggregation: wave w walks ITS dst's edges in this tile ----
        {
            int lo = dlo > tb ? dlo : tb;
            int hi = dhi < tb + tcnt ? dhi : tb + tcnt;
            int ib = lo - tb, ie = hi - tb;
            // hoist srcn into lane registers: one coalesced LDS read, then
            // shfl per iteration (no per-iteration LDS->global serial chain)
            int sidx = ib + lane; if (sidx > 63) sidx = 63;
            const int srcreg = src_lds[sidx];
            #pragma unroll 4
            for (int i = ib; i < ie; i++) {
                const int srcn = __shfl(srcreg, i - ib);
                const float y0  = y_lds[i][0];
                const float y1x = y_lds[i][1];
                const float y1y = y_lds[i][2];
                const float y1z = y_lds[i][3];
                const float* fsr = f_s + (size_t)srcn * 64;
                const float* fvr = f_v + (size_t)srcn * 96;
                const unsigned short* wrow = &w_lds[i * WL_STRIDE];

                // shared loads
                float fs_l  = fsr[lane];
                float fs_u0 = fsr[u0];
                float fs_uB = fsr[uB];
                float fs_u2 = fsr[u2];
                float fvA0 = fvr[lane2 * 3], fvA1 = fvr[lane2 * 3 + 1], fvA2 = fvr[lane2 * 3 + 2];
                float fvB0 = fvr[u0 * 3],    fvB1 = fvr[u0 * 3 + 1],    fvB2 = fvr[u0 * 3 + 2];
                float fvH0 = fvr[uH * 3],    fvH1 = fvr[uH * 3 + 1],    fvH2 = fvr[uH * 3 + 2];

                float y1c0 = (c0 == 0) ? y1x : (c0 == 1) ? y1y : y1z;
                float y1cB = (cB == 0) ? y1x : (cB == 1) ? y1y : y1z;
                float y1c2 = (c2 == 0) ? y1x : (c2 == 1) ? y1y : y1z;

                // w values (9 LDS ushorts)
                float w_s0 = bf2f(wrow[lane]);               // A  col = lane
                float w_s1 = bf2f(wrow[160 + lane2]);        // D  col = 160+u
                float w_s2 = bf2f(wrow[64 + u0]);            // B
                float w_s3 = bf2f(wrow[64 + uB]);
                float w_s4 = bf2f(wrow[64 + u2]);
                float w_s5 = bf2f(wrow[128 + u0]);           // C
                float w_s6 = bf2f(wrow[128 + uH]);
                float w_s7 = bf2f(wrow[192 + u0]);           // E
                float w_s8 = bf2f(wrow[192 + uH]);

                const float k14 = 0.25f;
                const float k13 = 0.25f * 0.57735026918962576451f;
                const float k12 = 0.25f * 0.70710678118654752440f;

                // s0: A  f=lane
                acc[0] = fmaf(w_s0 * fs_l, y0 * k14, acc[0]);
                // s1: D  f=64+lane (lane<32)
                {
                    float dot = fvA0 * y1x + fvA1 * y1y + fvA2 * y1z;
                    acc[1] = fmaf(w_s1 * dot, k13, acc[1]);
                }
                // s2..s4: B  agg_v flat {lane, 64+lane, 128+lane}
                acc[2] = fmaf(w_s2 * fs_u0, k14 * y1c0, acc[2]);
                acc[3] = fmaf(w_s3 * fs_uB, k14 * y1cB, acc[3]);
                acc[4] = fmaf(w_s4 * fs_u2, k14 * y1c2, acc[4]);
                // s5: C  flat 192+lane; s6: C flat 256+lane2 (lane<32)
                {
                    float e5 = (c0 == 0) ? fvB0 : (c0 == 1) ? fvB1 : fvB2;
                    float e6 = (cH == 0) ? fvH0 : (cH == 1) ? fvH1 : fvH2;
                    acc[5] = fmaf(w_s5 * e5, k14 * y0, acc[5]);
                    acc[6] = fmaf(w_s6 * e6, k14 * y0, acc[6]);
                }
                // s7: E  flat 288+lane; s8: E flat 352+lane2 (lane<32)
                {
                    float cr7 = (c0 == 0) ? (fvB1 * y1z - fvB2 * y1y)
                              : (c0 == 1) ? (fvB2 * y1x - fvB0 * y1z)
                                          : (fvB0 * y1y - fvB1 * y1x);
                    float cr8 = (cH == 0) ? (fvH1 * y1z - fvH2 * y1y)
                              : (cH == 1) ? (fvH2 * y1x - fvH0 * y1z)
                                          : (fvH0 * y1y - fvH1 * y1x);
                    acc[7] = fmaf(w_s7 * cr7, k12, acc[7]);
                    acc[8] = fmaf(w_s8 * cr8, k12, acc[8]);
                }
            }
        }
    }

    // ---- writeback + fused angle epilogue ----
    if (node < Nn) {
        float* as = agg_s + (size_t)node * MIDS;
        float* av = agg_v + (size_t)node * (MIDV * 3);
        as[lane] = acc[0];
        if (half) as[64 + lane] = acc[1];
        av[lane]       = acc[2];
        av[64 + lane]  = acc[3];
        av[128 + lane] = acc[4];
        av[192 + lane] = acc[5];
        if (half) av[256 + lane] = acc[6];
        av[288 + lane] = acc[7];
        if (half) av[352 + lane] = acc[8];

        // angle = 0.1 * (agg_s . Wl3) * attr  -> cos/sin
        float avv = acc[0] * Wl3[lane];
        if (half) avv = fmaf(acc[1], Wl3[64 + lane], avv);
        #pragma unroll
        for (int d = 1; d < 64; d <<= 1) avv += __shfl_xor(avv, d);
        if (lane == 0) {
            float at = isbf ? ldf<true>(attr, node) : ldf<false>(attr, node);
            float a = 0.1f * avv * at;
            cosb[node] = __cosf(a);
            sinb[node] = __sinf(a);
        }
    }
}

// ---------------- kernel 4: final output ----------------
template<bool BF>
__device__ __forceinline__ void final_body(
    const void* __restrict__ ns, const void* __restrict__ nv,
    const void* __restrict__ attr,
    const float* __restrict__ Wscs, const float* __restrict__ Wscv,
    const float* __restrict__ Wl2s, const float* __restrict__ Wl2v,
    const float* __restrict__ agg_s, const float* __restrict__ agg_v,
    const float* __restrict__ cosb, const float* __restrict__ sinb,
    void* __restrict__ out, int Nn)
{
    int i = blockIdx.x * 256 + threadIdx.x;
    int stotal = Nn * MUL0;
    if (i < stotal) {
        int n = i >> 6, j = i & 63;
        const float* ar = agg_s + (size_t)n * MIDS;
        float a1 = 0.f, a2 = 0.f;
        #pragma unroll
        for (int u = 0; u < MUL0; u++)
            a1 = fmaf(ldf<BF>(ns, (size_t)n * MUL0 + u), Wscs[u * MUL0 + j], a1);
        #pragma unroll
        for (int u = 0; u < MIDS; u++) a2 = fmaf(ar[u], Wl2s[u * MUL0 + j], a2);
        float o = ldf<BF>(attr, n) * (cosb[n] * a1 + sinb[n] * a2);
        stf<BF>(out, (size_t)n * 160 + j, o);
    } else {
        int m = i - stotal;
        if (m >= Nn * 96) return;
        int n = m / 96; int idx = m - n * 96;
        int vi = idx / 3; int c = idx - vi * 3;
        const float* ar = agg_v + (size_t)n * (MIDV * 3);
        float a1 = 0.f, a2 = 0.f;
        #pragma unroll
        for (int u = 0; u < MUL1; u++)
            a1 = fmaf(ldf<BF>(nv, (size_t)n * 96 + u * 3 + c), Wscv[u * MUL1 + vi], a1);
        #pragma unroll
        for (int u = 0; u < MIDV; u++) a2 = fmaf(ar[u * 3 + c], Wl2v[u * MUL1 + vi], a2);
        float o = ldf<BF>(attr, n) * (cosb[n] * a1 + sinb[n] * a2);
        stf<BF>(out, (size_t)n * 160 + 64 + idx, o);
    }
}
__global__ __launch_bounds__(256) void k_final(
    const void* ns, const void* nv, const void* attr,
    const float* Wscs, const float* Wscv,
    const float* Wl2s, const float* Wl2v,
    const float* agg_s, const float* agg_v,
    const float* cosb, const float* sinb,
    void* out, int Nn, const int* flag)
{
    if (*flag) final_body<true >(ns, nv, attr, Wscs, Wscv, Wl2s, Wl2v, agg_s, agg_v, cosb, sinb, out, Nn);
    else       final_body<false>(ns, nv, attr, Wscs, Wscv, Wl2s, Wl2v, agg_s, agg_v, cosb, sinb, out, Nn);
}

// ---------------- launch ----------------
extern "C" void kernel_launch(void* const* d_in, const int* in_sizes, int n_in,
                              void* d_out, int out_size, void* d_ws, size_t ws_size,
                              hipStream_t stream)
{
    const void* ns    = d_in[0];
    const void* nv    = d_in[1];
    const void* attr  = d_in[2];
    const int*  esrc  = (const int*)d_in[3];
    const int*  edst  = (const int*)d_in[4];
    const void* eattr = d_in[5];
    const void* escal = d_in[6];

    const int Nn   = in_sizes[2];   // node_attr is (N,1)
    const int Ecnt = in_sizes[3];   // edge_src is (E,)

    float* ws = (float*)d_ws;
    int* flag = (int*)(ws + OFF_FLAG);
    unsigned short* w1frag = (unsigned short*)(ws + OFF_W1FRAG);
    unsigned short* w2frag = (unsigned short*)(ws + OFF_W2FRAG);

    const size_t OFF_FS   = OFF_DYN;
    const size_t OFF_FV   = OFF_FS   + (size_t)Nn * 64;
    const size_t OFF_AGGS = OFF_FV   + (size_t)Nn * 96;
    const size_t OFF_AGGV = OFF_AGGS + (size_t)Nn * 96;
    const size_t OFF_COS  = OFF_AGGV + (size_t)Nn * 384;
    const size_t OFF_SIN  = OFF_COS  + (size_t)Nn;
    const size_t OFF_CNT  = OFF_SIN  + (size_t)Nn;       // int[Nn]
    const size_t OFF_ROW  = OFF_CNT  + (size_t)Nn;       // int[Nn+1]
    const size_t OFF_CUR  = OFF_ROW  + (size_t)Nn + 1;   // int[Nn]
    const size_t OFF_PERM = OFF_CUR  + (size_t)Nn;       // int[Ecnt]

    int* cnt       = (int*)(ws + OFF_CNT);
    int* row_start = (int*)(ws + OFF_ROW);
    int* cur       = (int*)(ws + OFF_CUR);
    int* perm      = (int*)(ws + OFF_PERM);

    // fused prep: probe + convert + frag build + cnt zero + node precompute
    const int prep_work = Nn * 160 + OFF_WEND + W1FRAG_N + W2FRAG_N + Nn;
    k_prep<<<(prep_work + 255) / 256, 256, 0, stream>>>(
        ns, nv, attr,
        d_in[7], d_in[8], d_in[9], d_in[10], d_in[11], d_in[12],
        d_in[13], d_in[14], d_in[15],
        ws, w1frag, w2frag, cnt, flag,
        ws + OFF_FS, ws + OFF_FV, Nn);

    // CSR by dst
    k_hist<<<(Ecnt + 255) / 256, 256, 0, stream>>>(edst, cnt, Ecnt);
    k_scan<<<1, 1024, 0, stream>>>(cnt, row_start, cur, Nn);
    k_place<<<(Ecnt + 255) / 256, 256, 0, stream>>>(edst, row_start, cur, perm, Ecnt);

    k_edge_mfma<<<(Nn + EG - 1) / EG, 256, 0, stream>>>(
        escal, eattr, attr, esrc, row_start, perm, w1frag, w2frag,
        ws + OFF_WL3,
        ws + OFF_FS, ws + OFF_FV,
        ws + OFF_AGGS, ws + OFF_AGGV, ws + OFF_COS, ws + OFF_SIN,
        Nn, flag);

    k_final<<<((Nn * 160) + 255) / 256, 256, 0, stream>>>(
        ns, nv, attr,
        ws + OFF_WSCS, ws + OFF_WSCV, ws + OFF_WL2S, ws + OFF_WL2V,
        ws + OFF_AGGS, ws + OFF_AGGV, ws + OFF_COS, ws + OFF_SIN,
        (void*)d_out, Nn, flag);
}

// Round 9
// 599.706 us; speedup vs baseline: 5.5612x; 1.0702x over previous
//
#include <hip/hip_runtime.h>

// ---------------- problem constants ----------------
#define MUL0 64
#define MUL1 32
#define NBASIS 10
#define FCH 100
#define WNUMEL 224   // 2*MUL0 + 3*MUL1
#define MIDS 96      // MUL0 + MUL1
#define MIDV 128     // MUL0 + 2*MUL1
#define EG 4         // dst nodes per workgroup (one per wave)

// weight table offsets inside ws (floats), in d_in[7..15] order
#define OFF_W1   0        // W_fc1  10x100  (1000)
#define OFF_W2   1000     // W_fc2  100x224 (22400)
#define OFF_WSCS 23400    // W_sc_s 64x64   (4096)
#define OFF_WSCV 27496    // W_sc_v 32x32   (1024)
#define OFF_WL1S 28520    // W_l1_s 64x64   (4096)
#define OFF_WL1V 32616    // W_l1_v 32x32   (1024)
#define OFF_WL2S 33640    // W_l2_s 96x64   (6144)
#define OFF_WL2V 39784    // W_l2_v 128x32  (4096)
#define OFF_WL3  43880    // W_l3   96x1    (96)
#define OFF_WEND 43976
#define OFF_FLAG 43980    // dtype flag (int)
#define OFF_W1FRAG 44032  // bf16 frag layout, 3584 ushorts = 1792 floats
#define OFF_W2FRAG 45824  // bf16 frag layout, 28672 ushorts = 14336 floats
#define OFF_DYN  60160    // start of per-node buffers

#define W1FRAG_N (112 * 32)       // 3584
#define W2FRAG_N (4 * 224 * 32)   // 28672

typedef __attribute__((ext_vector_type(8))) short short8;
typedef __attribute__((ext_vector_type(4))) float f32x4;

// ---------------- helpers ----------------
__device__ __forceinline__ float bf2f(unsigned short h) {
    unsigned int u = ((unsigned int)h) << 16;
    float f; __builtin_memcpy(&f, &u, 4); return f;
}
__device__ __forceinline__ unsigned short f2bf(float f) {
    unsigned int u; __builtin_memcpy(&u, &f, 4);
    u += 0x7fffu + ((u >> 16) & 1u);   // round-to-nearest-even
    return (unsigned short)(u >> 16);
}
__device__ __forceinline__ float fast_silu(float x) {
    return x * __builtin_amdgcn_rcpf(1.0f + __expf(-x));
}
template<bool BF>
__device__ __forceinline__ float ldf(const void* p, size_t i) {
    if constexpr (BF) return bf2f(((const unsigned short*)p)[i]);
    else              return ((const float*)p)[i];
}
template<bool BF>
__device__ __forceinline__ void stf(void* p, size_t i, float v) {
    if constexpr (BF) ((unsigned short*)p)[i] = f2bf(v);
    else              ((float*)p)[i] = v;
}
__device__ __forceinline__ int wave_incl_scan(int v) {
    int lane = threadIdx.x & 63;
    #pragma unroll
    for (int d = 1; d < 64; d <<= 1) {
        int t = __shfl_up(v, d, 64);
        if (lane >= d) v += t;
    }
    return v;
}

// ---------------- node precompute body (reads RAW inputs only) -------------
template<bool BF>
__device__ __forceinline__ void node_pre_body(
    const void* __restrict__ ns, const void* __restrict__ nv,
    const void* __restrict__ attr,
    const void* __restrict__ Wl1s, const void* __restrict__ Wl1v,
    float* __restrict__ f_s, float* __restrict__ f_v, int i, int Nn)
{
    int stotal = Nn * MUL0;
    if (i < stotal) {
        int n = i >> 6, j = i & 63;
        float a = 0.f;
        #pragma unroll
        for (int u = 0; u < MUL0; u++)
            a = fmaf(ldf<BF>(ns, (size_t)n * MUL0 + u), ldf<BF>(Wl1s, u * MUL0 + j), a);
        f_s[i] = a * ldf<BF>(attr, n);
    } else {
        int m = i - stotal;
        if (m >= Nn * MUL1 * 3) return;
        int n = m / 96; int idx = m - n * 96;
        int vi = idx / 3; int c = idx - vi * 3;
        float a = 0.f;
        #pragma unroll
        for (int u = 0; u < MUL1; u++)
            a = fmaf(ldf<BF>(nv, (size_t)n * 96 + u * 3 + c), ldf<BF>(Wl1v, u * MUL1 + vi), a);
        f_v[m] = a * ldf<BF>(attr, n);
    }
}

// ---------------- k_prep: probe + convert + frag build + cnt zero + node pre
__global__ __launch_bounds__(256) void k_prep(
    const void* __restrict__ ns, const void* __restrict__ nv,
    const void* __restrict__ attr,
    const void* __restrict__ a0, const void* __restrict__ a1,
    const void* __restrict__ a2, const void* __restrict__ a3,
    const void* __restrict__ a4, const void* __restrict__ a5,
    const void* __restrict__ a6, const void* __restrict__ a7,
    const void* __restrict__ a8,
    float* __restrict__ wsf,
    unsigned short* __restrict__ w1frag, unsigned short* __restrict__ w2frag,
    int* __restrict__ cnt, int* __restrict__ flag,
    float* __restrict__ f_s, float* __restrict__ f_v, int Nn)
{
    const bool bf = (((const unsigned int*)attr)[0] == 0x3F803F80u);
    int i = blockIdx.x * 256 + threadIdx.x;
    if (i == 0) *flag = bf ? 1 : 0;

    const int npre = Nn * 160;
    if (i < npre) {
        if (bf) node_pre_body<true >(ns, nv, attr, a4, a5, f_s, f_v, i, Nn);
        else    node_pre_body<false>(ns, nv, attr, a4, a5, f_s, f_v, i, Nn);
        return;
    }
    int m = i - npre;
    if (m < OFF_WEND) {
        const void* p; int off = m;
        if      (m < OFF_W2)   { p = a0; }
        else if (m < OFF_WSCS) { p = a1; off = m - OFF_W2; }
        else if (m < OFF_WSCV) { p = a2; off = m - OFF_WSCS; }
        else if (m < OFF_WL1S) { p = a3; off = m - OFF_WSCV; }
        else if (m < OFF_WL1V) { p = a4; off = m - OFF_WL1S; }
        else if (m < OFF_WL2S) { p = a5; off = m - OFF_WL1V; }
        else if (m < OFF_WL2V) { p = a6; off = m - OFF_WL2S; }
        else if (m < OFF_WL3)  { p = a7; off = m - OFF_WL2V; }
        else                   { p = a8; off = m - OFF_WL3; }
        wsf[m] = bf ? ldf<true>(p, off) : ldf<false>(p, off);
        return;
    }
    m -= OFF_WEND;
    if (m < W1FRAG_N) {
        int col = m >> 5, k = m & 31;
        float v = 0.f;
        if (col < FCH && k < NBASIS)
            v = bf ? ldf<true>(a0, k * FCH + col) : ldf<false>(a0, k * FCH + col);
        w1frag[m] = f2bf(v);
        return;
    }
    m -= W1FRAG_N;
    if (m < W2FRAG_N) {
        int q = m / (224 * 32); int r = m - q * 224 * 32;
        int n = r >> 5; int kk = r & 31;
        int k = q * 32 + kk;
        float v = 0.f;
        if (k < FCH)
            v = bf ? ldf<true>(a1, k * WNUMEL + n) : ldf<false>(a1, k * WNUMEL + n);
        w2frag[m] = f2bf(v);
        return;
    }
    m -= W2FRAG_N;
    if (m < Nn) cnt[m] = 0;
}

// ---------------- CSR: histogram ----------------
__global__ __launch_bounds__(256) void k_hist(
    const int* __restrict__ edst, int* __restrict__ cnt, int Ecnt)
{
    int e = blockIdx.x * 256 + threadIdx.x;
    if (e < Ecnt) atomicAdd(&cnt[edst[e]], 1);
}

// ---------------- 3-phase parallel scan (replaces single-wg scan) ----------
__global__ __launch_bounds__(256) void k_scan_blk(
    const int* __restrict__ cnt, int* __restrict__ row_part,
    int* __restrict__ blk_sum, int Nn)
{
    __shared__ int ws4[4];
    int tid = threadIdx.x, lane = tid & 63, wid = tid >> 6;
    int i = blockIdx.x * 256 + tid;
    int v = (i < Nn) ? cnt[i] : 0;
    int incl = wave_incl_scan(v);
    if (lane == 63) ws4[wid] = incl;
    __syncthreads();
    int off = 0;
    #pragma unroll
    for (int w2 = 0; w2 < 4; w2++) off += (w2 < wid) ? ws4[w2] : 0;
    if (i < Nn) row_part[i] = off + incl - v;
    if (tid == 0) blk_sum[blockIdx.x] = ws4[0] + ws4[1] + ws4[2] + ws4[3];
}

__global__ __launch_bounds__(256) void k_scan_top(
    const int* __restrict__ blk_sum, int* __restrict__ blk_off,
    int* __restrict__ row_start, int NB, int Nn)
{
    __shared__ int ws4[4];
    int tid = threadIdx.x, lane = tid & 63, wid = tid >> 6;
    int v = (tid < NB) ? blk_sum[tid] : 0;
    int incl = wave_incl_scan(v);
    if (lane == 63) ws4[wid] = incl;
    __syncthreads();
    int off = 0;
    #pragma unroll
    for (int w2 = 0; w2 < 4; w2++) off += (w2 < wid) ? ws4[w2] : 0;
    if (tid < NB) blk_off[tid] = off + incl - v;
    if (tid == 0) row_start[Nn] = ws4[0] + ws4[1] + ws4[2] + ws4[3];
}

__global__ __launch_bounds__(256) void k_rowfix(
    const int* __restrict__ row_part, const int* __restrict__ blk_off,
    int* __restrict__ row_start, int* __restrict__ cur, int Nn)
{
    int i = blockIdx.x * 256 + threadIdx.x;
    if (i < Nn) { row_start[i] = blk_off[i >> 8] + row_part[i]; cur[i] = 0; }
}

// ---------------- fallback single-wg scan (old path) ----------------
__global__ __launch_bounds__(1024) void k_scan1(
    const int* __restrict__ cnt, int* __restrict__ row_start,
    int* __restrict__ cur, int Nn)
{
    __shared__ int wsum[16];
    __shared__ int s_off, s_tot;
    int tid = threadIdx.x, lane = tid & 63, wid = tid >> 6;
    if (tid == 0) s_off = 0;
    __syncthreads();
    for (int base = 0; base < Nn; base += 1024) {
        int i = base + tid;
        int v = (i < Nn) ? cnt[i] : 0;
        int incl = wave_incl_scan(v);
        if (lane == 63) wsum[wid] = incl;
        __syncthreads();
        if (wid == 0) {
            int wv = (lane < 16) ? wsum[lane] : 0;
            int wincl = wave_incl_scan(wv);
            if (lane < 16) wsum[lane] = wincl - wv;
            if (lane == 15) s_tot = wincl;
        }
        __syncthreads();
        int excl = s_off + wsum[wid] + incl - v;
        if (i < Nn) { row_start[i] = excl; cur[i] = 0; }
        __syncthreads();
        if (tid == 0) s_off += s_tot;
        __syncthreads();
    }
    if (threadIdx.x == 0) row_start[Nn] = s_off;
}

// ---------------- k_place (+ optional src/y sidecars for the split path) ---
__global__ __launch_bounds__(256) void k_place(
    const int* __restrict__ edst, const int* __restrict__ esrc,
    const void* __restrict__ eattr,
    const int* __restrict__ row_start, int* __restrict__ cur,
    int* __restrict__ perm, int* __restrict__ srcs, float* __restrict__ y4,
    int Ecnt, const int* __restrict__ flag, int extras)
{
    int e = blockIdx.x * 256 + threadIdx.x;
    if (e >= Ecnt) return;
    int d = edst[e];
    int pos = row_start[d] + atomicAdd(&cur[d], 1);
    perm[pos] = e;
    if (extras) {
        srcs[pos] = esrc[e];
        float4 yv;
        if (*flag) {
            const unsigned short* ap = (const unsigned short*)eattr + (size_t)e * 4;
            yv = make_float4(bf2f(ap[0]), bf2f(ap[1]), bf2f(ap[2]), bf2f(ap[3]));
        } else {
            const float* ap = (const float*)eattr + (size_t)e * 4;
            yv = make_float4(ap[0], ap[1], ap[2], ap[3]);
        }
        ((float4*)y4)[pos] = yv;
    }
}

// ---------------- k_fc: dense per-edge MLP (MFMA), wbuf in CSR order -------
#define HFC_STRIDE 136   // 272 B rows, 16B-aligned

__global__ __launch_bounds__(256) void k_fc(
    const void* __restrict__ escal, const int* __restrict__ perm,
    const unsigned short* __restrict__ w1frag, const unsigned short* __restrict__ w2frag,
    unsigned short* __restrict__ wbuf, int Ecnt, const int* __restrict__ flag)
{
    __shared__ __align__(16) unsigned short h_lds[64 * HFC_STRIDE]; // 17.4 KB
    const int tid  = threadIdx.x;
    const int lane = tid & 63;
    const int wave = tid >> 6;
    const int nl   = lane & 15;
    const int quad = lane >> 4;
    const int tb   = blockIdx.x * 64;

    // zero h padding cols 112..127
    for (int i = tid; i < 64 * 16; i += 256) {
        int row = i >> 4;
        h_lds[row * HFC_STRIDE + 112 + (i & 15)] = 0;
    }

    // load es A-fragment straight from global (k rows 10..31 are zero)
    int eidx = tb + 16 * wave + nl;
    if (eidx >= Ecnt) eidx = Ecnt - 1;
    const int e = perm[eidx];
    short8 a = {0, 0, 0, 0, 0, 0, 0, 0};
    if (*flag) {
        const unsigned int* p = (const unsigned int*)((const unsigned short*)escal + (size_t)e * NBASIS);
        if (quad == 0) {
            unsigned int d0 = p[0], d1 = p[1], d2 = p[2], d3 = p[3];
            a = (short8){(short)d0, (short)(d0 >> 16), (short)d1, (short)(d1 >> 16),
                         (short)d2, (short)(d2 >> 16), (short)d3, (short)(d3 >> 16)};
        } else if (quad == 1) {
            unsigned int d4 = p[4];
            a = (short8){(short)d4, (short)(d4 >> 16), 0, 0, 0, 0, 0, 0};
        }
    } else {
        const float* p = (const float*)escal + (size_t)e * NBASIS;
        if (quad == 0) {
            a = (short8){(short)f2bf(p[0]), (short)f2bf(p[1]), (short)f2bf(p[2]), (short)f2bf(p[3]),
                         (short)f2bf(p[4]), (short)f2bf(p[5]), (short)f2bf(p[6]), (short)f2bf(p[7])};
        } else if (quad == 1) {
            a = (short8){(short)f2bf(p[8]), (short)f2bf(p[9]), 0, 0, 0, 0, 0, 0};
        }
    }

    // FC1: 7 col-tiles
    {
        f32x4 hacc[7];
        #pragma unroll
        for (int t = 0; t < 7; t++) {
            short8 b = *(const short8*)&w1frag[(16 * t + nl) * 32 + quad * 8];
            hacc[t] = __builtin_amdgcn_mfma_f32_16x16x32_bf16(
                a, b, (f32x4){0.f, 0.f, 0.f, 0.f}, 0, 0, 0);
        }
        #pragma unroll
        for (int t = 0; t < 7; t++) {
            #pragma unroll
            for (int r = 0; r < 4; r++)
                h_lds[(16 * wave + quad * 4 + r) * HFC_STRIDE + 16 * t + nl] =
                    f2bf(fast_silu(hacc[t][r]));
        }
    }
    __syncthreads();

    // FC2: 14 col-tiles x 4 ksteps -> wbuf rows (CSR order)
    #pragma unroll 2
    for (int t = 0; t < 14; t++) {
        f32x4 c = {0.f, 0.f, 0.f, 0.f};
        #pragma unroll
        for (int q = 0; q < 4; q++) {
            short8 av = *(const short8*)&h_lds[(16 * wave + nl) * HFC_STRIDE + q * 32 + quad * 8];
            short8 b = *(const short8*)&w2frag[((q * 224) + 16 * t + nl) * 32 + quad * 8];
            c = __builtin_amdgcn_mfma_f32_16x16x32_bf16(av, b, c, 0, 0, 0);
        }
        #pragma unroll
        for (int r = 0; r < 4; r++)
            wbuf[(size_t)(tb + 16 * wave + quad * 4 + r) * WNUMEL + 16 * t + nl] = f2bf(c[r]);
    }
}

// ---------------- k_agg: one wave per dst, no LDS, no barriers -------------
__global__ __launch_bounds__(256) void k_agg(
    const unsigned short* __restrict__ wbuf,
    const int* __restrict__ srcs, const float* __restrict__ y4,
    const int* __restrict__ row_start,
    const float* __restrict__ f_s, const float* __restrict__ f_v,
    const float* __restrict__ Wl3, const void* __restrict__ attr,
    float* __restrict__ agg_s, float* __restrict__ agg_v,
    float* __restrict__ cosb, float* __restrict__ sinb,
    int Nn, const int* __restrict__ flag)
{
    const int tid  = threadIdx.x;
    const int lane = tid & 63;
    const int wave = tid >> 6;
    const int node = blockIdx.x * EG + wave;
    if (node >= Nn) return;

    // slice constants (lane-derived, branch-free) — identical to round 8
    const int lane2 = lane & 31;
    const int u0 = lane / 3,  c0 = lane - 3 * u0;
    const int pB = 64 + lane;
    const int uB = pB / 3,    cB = pB - 3 * uB;
    const int p2 = 128 + lane;
    const int u2 = p2 / 3,    c2 = p2 - 3 * u2;
    const int pH = 64 + lane2;
    const int uH = pH / 3,    cH = pH - 3 * uH;
    const bool half = (lane < 32);

    const int dlo = row_start[node];
    const int dhi = row_start[node + 1];

    float acc[9];
    #pragma unroll
    for (int s = 0; s < 9; s++) acc[s] = 0.f;

    const float k14 = 0.25f;
    const float k13 = 0.25f * 0.57735026918962576451f;
    const float k12 = 0.25f * 0.70710678118654752440f;

    for (int idx = dlo; idx < dhi; idx++) {
        const int srcn = srcs[idx];
        const float4 y = ((const float4*)y4)[idx];
        const float y0 = y.x, y1x = y.y, y1y = y.z, y1z = y.w;
        const unsigned short* wrow = wbuf + (size_t)idx * WNUMEL;
        const float* fsr = f_s + (size_t)srcn * 64;
        const float* fvr = f_v + (size_t)srcn * 96;

        // coalesced row loads + shfl extraction (replaces 12 gathers with 3 loads)
        float fs_l = fsr[lane];
        float fv_a = fvr[lane];
        float fv_b = (lane < 32) ? fvr[64 + lane] : 0.f;

        float fs_u0 = __shfl(fs_l, u0);
        float fs_uB = __shfl(fs_l, uB);
        float fs_u2 = __shfl(fs_l, u2);
        auto fvel = [&](int j) -> float {
            float va = __shfl(fv_a, j & 63);
            float vb = __shfl(fv_b, j & 63);
            return (j < 64) ? va : vb;
        };
        float fvA0 = fvel(3 * lane2), fvA1 = fvel(3 * lane2 + 1), fvA2 = fvel(3 * lane2 + 2);
        float fvB0 = fvel(3 * u0),    fvB1 = fvel(3 * u0 + 1),    fvB2 = fvel(3 * u0 + 2);
        float fvH0 = fvel(3 * uH),    fvH1 = fvel(3 * uH + 1),    fvH2 = fvel(3 * uH + 2);

        float y1c0 = (c0 == 0) ? y1x : (c0 == 1) ? y1y : y1z;
        float y1cB = (cB == 0) ? y1x : (cB == 1) ? y1y : y1z;
        float y1c2 = (c2 == 0) ? y1x : (c2 == 1) ? y1y : y1z;

        // w values: 9 scalar loads from the streaming wbuf row
        float w_s0 = bf2f(wrow[lane]);
        float w_s1 = bf2f(wrow[160 + lane2]);
        float w_s2 = bf2f(wrow[64 + u0]);
        float w_s3 = bf2f(wrow[64 + uB]);
        float w_s4 = bf2f(wrow[64 + u2]);
        float w_s5 = bf2f(wrow[128 + u0]);
        float w_s6 = bf2f(wrow[128 + uH]);
        float w_s7 = bf2f(wrow[192 + u0]);
        float w_s8 = bf2f(wrow[192 + uH]);

        acc[0] = fmaf(w_s0 * fs_l, y0 * k14, acc[0]);
        {
            float dot = fvA0 * y1x + fvA1 * y1y + fvA2 * y1z;
            acc[1] = fmaf(w_s1 * dot, k13, acc[1]);
        }
        acc[2] = fmaf(w_s2 * fs_u0, k14 * y1c0, acc[2]);
        acc[3] = fmaf(w_s3 * fs_uB, k14 * y1cB, acc[3]);
        acc[4] = fmaf(w_s4 * fs_u2, k14 * y1c2, acc[4]);
        {
            float e5 = (c0 == 0) ? fvB0 : (c0 == 1) ? fvB1 : fvB2;
            float e6 = (cH == 0) ? fvH0 : (cH == 1) ? fvH1 : fvH2;
            acc[5] = fmaf(w_s5 * e5, k14 * y0, acc[5]);
            acc[6] = fmaf(w_s6 * e6, k14 * y0, acc[6]);
        }
        {
            float cr7 = (c0 == 0) ? (fvB1 * y1z - fvB2 * y1y)
                      : (c0 == 1) ? (fvB2 * y1x - fvB0 * y1z)
                                  : (fvB0 * y1y - fvB1 * y1x);
            float cr8 = (cH == 0) ? (fvH1 * y1z - fvH2 * y1y)
                      : (cH == 1) ? (fvH2 * y1x - fvH0 * y1z)
                                  : (fvH0 * y1y - fvH1 * y1x);
            acc[7] = fmaf(w_s7 * cr7, k12, acc[7]);
            acc[8] = fmaf(w_s8 * cr8, k12, acc[8]);
        }
    }

    // writeback + fused angle epilogue
    {
        float* as = agg_s + (size_t)node * MIDS;
        float* av = agg_v + (size_t)node * (MIDV * 3);
        as[lane] = acc[0];
        if (half) as[64 + lane] = acc[1];
        av[lane]       = acc[2];
        av[64 + lane]  = acc[3];
        av[128 + lane] = acc[4];
        av[192 + lane] = acc[5];
        if (half) av[256 + lane] = acc[6];
        av[288 + lane] = acc[7];
        if (half) av[352 + lane] = acc[8];

        float avv = acc[0] * Wl3[lane];
        if (half) avv = fmaf(acc[1], Wl3[64 + lane], avv);
        #pragma unroll
        for (int d = 1; d < 64; d <<= 1) avv += __shfl_xor(avv, d);
        if (lane == 0) {
            float at = (*flag) ? ldf<true>(attr, node) : ldf<false>(attr, node);
            float aa = 0.1f * avv * at;
            cosb[node] = __cosf(aa);
            sinb[node] = __sinf(aa);
        }
    }
}

// ---------------- fallback fused edge kernel (round-8, verbatim) -----------
#define ES_STRIDE 40
#define H_STRIDE 136
#define WL_STRIDE 225

__global__ __launch_bounds__(256) void k_edge_mfma(
    const void* __restrict__ escal, const void* __restrict__ eattr,
    const void* __restrict__ attr,
    const int* __restrict__ esrc,
    const int* __restrict__ row_start, const int* __restrict__ perm,
    const unsigned short* __restrict__ w1frag, const unsigned short* __restrict__ w2frag,
    const float* __restrict__ Wl3,
    const float* __restrict__ f_s, const float* __restrict__ f_v,
    float* __restrict__ agg_s, float* __restrict__ agg_v,
    float* __restrict__ cosb, float* __restrict__ sinb,
    int Nn, const int* __restrict__ flag)
{
    __shared__ __align__(16) unsigned short es_lds[64 * ES_STRIDE];
    __shared__ __align__(16) unsigned short h_lds[64 * H_STRIDE];
    __shared__ __align__(16) unsigned short w_lds[64 * WL_STRIDE];
    __shared__ float y_lds[64][4];
    __shared__ int   src_lds[64];

    const int tid  = threadIdx.x;
    const int lane = tid & 63;
    const int wave = tid >> 6;
    const int nl   = lane & 15;
    const int quad = lane >> 4;
    const int gbase = blockIdx.x * EG;
    const bool isbf = (*flag != 0);

    for (int i = tid; i < 64 * 22; i += 256) {
        int row = i / 22, k = 10 + (i - row * 22);
        es_lds[row * ES_STRIDE + k] = 0;
    }
    for (int i = tid; i < 64 * 16; i += 256) {
        int row = i >> 4, k = 112 + (i & 15);
        h_lds[row * H_STRIDE + k] = 0;
    }

    const int lane2 = lane & 31;
    const int u0 = lane / 3,  c0 = lane - 3 * u0;
    const int pB = 64 + lane;
    const int uB = pB / 3,    cB = pB - 3 * uB;
    const int p2 = 128 + lane;
    const int u2 = p2 / 3,    c2 = p2 - 3 * u2;
    const int pH = 64 + lane2;
    const int uH = pH / 3,    cH = pH - 3 * uH;
    const bool half = (lane < 32);

    const int node = gbase + wave;
    const int dlo = (node < Nn) ? row_start[node] : 0;
    const int dhi = (node < Nn) ? row_start[node + 1] : 0;

    float acc[9];
    #pragma unroll
    for (int s = 0; s < 9; s++) acc[s] = 0.f;

    const int gend    = (gbase + EG < Nn) ? (gbase + EG) : Nn;
    const int e_start = row_start[gbase];
    const int e_end   = row_start[gend];

    for (int tb = e_start; tb < e_end; tb += 64) {
        const int tcnt = (e_end - tb < 64) ? (e_end - tb) : 64;
        __syncthreads();

        {
            int i = tid & 63, part = tid >> 6;
            if (i < tcnt && part < 2) {
                int e = perm[tb + i];
                if (part == 0) {
                    unsigned int* dstp = (unsigned int*)&es_lds[i * ES_STRIDE];
                    if (isbf) {
                        const unsigned int* srcp =
                            (const unsigned int*)((const unsigned short*)escal + (size_t)e * NBASIS);
                        #pragma unroll
                        for (int t2 = 0; t2 < 5; t2++) dstp[t2] = srcp[t2];
                    } else {
                        const float* srcp = (const float*)escal + (size_t)e * NBASIS;
                        #pragma unroll
                        for (int t2 = 0; t2 < 5; t2++) {
                            unsigned int lo = f2bf(srcp[2 * t2]);
                            unsigned int hi = f2bf(srcp[2 * t2 + 1]);
                            dstp[t2] = lo | (hi << 16);
                        }
                    }
                } else {
                    src_lds[i] = esrc[e];
                    if (isbf) {
                        const unsigned short* ap = (const unsigned short*)eattr + (size_t)e * 4;
                        #pragma unroll
                        for (int t2 = 0; t2 < 4; t2++) y_lds[i][t2] = bf2f(ap[t2]);
                    } else {
                        const float* ap = (const float*)eattr + (size_t)e * 4;
                        #pragma unroll
                        for (int t2 = 0; t2 < 4; t2++) y_lds[i][t2] = ap[t2];
                    }
                }
            }
        }
        __syncthreads();

        {
            short8 a = *(const short8*)&es_lds[(16 * wave + nl) * ES_STRIDE + quad * 8];
            f32x4 hacc[7];
            #pragma unroll
            for (int t = 0; t < 7; t++) {
                short8 b = *(const short8*)&w1frag[(16 * t + nl) * 32 + quad * 8];
                hacc[t] = __builtin_amdgcn_mfma_f32_16x16x32_bf16(
                    a, b, (f32x4){0.f, 0.f, 0.f, 0.f}, 0, 0, 0);
            }
            #pragma unroll
            for (int t = 0; t < 7; t++) {
                #pragma unroll
                for (int r = 0; r < 4; r++)
                    h_lds[(16 * wave + quad * 4 + r) * H_STRIDE + 16 * t + nl] =
                        f2bf(fast_silu(hacc[t][r]));
            }
        }
        __syncthreads();

        #pragma unroll 2
        for (int t = 0; t < 14; t++) {
            f32x4 c = {0.f, 0.f, 0.f, 0.f};
            #pragma unroll
            for (int q = 0; q < 4; q++) {
                short8 a = *(const short8*)&h_lds[(16 * wave + nl) * H_STRIDE + q * 32 + quad * 8];
                short8 b = *(const short8*)&w2frag[((q * 224) + 16 * t + nl) * 32 + quad * 8];
                c = __builtin_amdgcn_mfma_f32_16x16x32_bf16(a, b, c, 0, 0, 0);
            }
            #pragma unroll
            for (int r = 0; r < 4; r++)
                w_lds[(16 * wave + quad * 4 + r) * WL_STRIDE + 16 * t + nl] = f2bf(c[r]);
        }
        __syncthreads();

        {
            int lo = dlo > tb ? dlo : tb;
            int hi = dhi < tb + tcnt ? dhi : tb + tcnt;
            for (int idx = lo; idx < hi; idx++) {
                const int i = idx - tb;
                const int srcn = src_lds[i];
                const float y0  = y_lds[i][0];
                const float y1x = y_lds[i][1];
                const float y1y = y_lds[i][2];
                const float y1z = y_lds[i][3];
                const float* fsr = f_s + (size_t)srcn * 64;
                const float* fvr = f_v + (size_t)srcn * 96;
                const unsigned short* wrow = &w_lds[i * WL_STRIDE];

                float fs_l  = fsr[lane];
                float fs_u0 = fsr[u0];
                float fs_uB = fsr[uB];
                float fs_u2 = fsr[u2];
                float fvA0 = fvr[lane2 * 3], fvA1 = fvr[lane2 * 3 + 1], fvA2 = fvr[lane2 * 3 + 2];
                float fvB0 = fvr[u0 * 3],    fvB1 = fvr[u0 * 3 + 1],    fvB2 = fvr[u0 * 3 + 2];
                float fvH0 = fvr[uH * 3],    fvH1 = fvr[uH * 3 + 1],    fvH2 = fvr[uH * 3 + 2];

                float y1c0 = (c0 == 0) ? y1x : (c0 == 1) ? y1y : y1z;
                float y1cB = (cB == 0) ? y1x : (cB == 1) ? y1y : y1z;
                float y1c2 = (c2 == 0) ? y1x : (c2 == 1) ? y1y : y1z;

                float w_s0 = bf2f(wrow[lane]);
                float w_s1 = bf2f(wrow[160 + lane2]);
                float w_s2 = bf2f(wrow[64 + u0]);
                float w_s3 = bf2f(wrow[64 + uB]);
                float w_s4 = bf2f(wrow[64 + u2]);
                float w_s5 = bf2f(wrow[128 + u0]);
                float w_s6 = bf2f(wrow[128 + uH]);
                float w_s7 = bf2f(wrow[192 + u0]);
                float w_s8 = bf2f(wrow[192 + uH]);

                const float k14 = 0.25f;
                const float k13 = 0.25f * 0.57735026918962576451f;
                const float k12 = 0.25f * 0.70710678118654752440f;

                acc[0] = fmaf(w_s0 * fs_l, y0 * k14, acc[0]);
                {
                    float dot = fvA0 * y1x + fvA1 * y1y + fvA2 * y1z;
                    acc[1] = fmaf(w_s1 * dot, k13, acc[1]);
                }
                acc[2] = fmaf(w_s2 * fs_u0, k14 * y1c0, acc[2]);
                acc[3] = fmaf(w_s3 * fs_uB, k14 * y1cB, acc[3]);
                acc[4] = fmaf(w_s4 * fs_u2, k14 * y1c2, acc[4]);
                {
                    float e5 = (c0 == 0) ? fvB0 : (c0 == 1) ? fvB1 : fvB2;
                    float e6 = (cH == 0) ? fvH0 : (cH == 1) ? fvH1 : fvH2;
                    acc[5] = fmaf(w_s5 * e5, k14 * y0, acc[5]);
                    acc[6] = fmaf(w_s6 * e6, k14 * y0, acc[6]);
                }
                {
                    float cr7 = (c0 == 0) ? (fvB1 * y1z - fvB2 * y1y)
                              : (c0 == 1) ? (fvB2 * y1x - fvB0 * y1z)
                                          : (fvB0 * y1y - fvB1 * y1x);
                    float cr8 = (cH == 0) ? (fvH1 * y1z - fvH2 * y1y)
                              : (cH == 1) ? (fvH2 * y1x - fvH0 * y1z)
                                          : (fvH0 * y1y - fvH1 * y1x);
                    acc[7] = fmaf(w_s7 * cr7, k12, acc[7]);
                    acc[8] = fmaf(w_s8 * cr8, k12, acc[8]);
                }
            }
        }
    }

    if (node < Nn) {
        float* as = agg_s + (size_t)node * MIDS;
        float* av = agg_v + (size_t)node * (MIDV * 3);
        as[lane] = acc[0];
        if (half) as[64 + lane] = acc[1];
        av[lane]       = acc[2];
        av[64 + lane]  = acc[3];
        av[128 + lane] = acc[4];
        av[192 + lane] = acc[5];
        if (half) av[256 + lane] = acc[6];
        av[288 + lane] = acc[7];
        if (half) av[352 + lane] = acc[8];

        float avv = acc[0] * Wl3[lane];
        if (half) avv = fmaf(acc[1], Wl3[64 + lane], avv);
        #pragma unroll
        for (int d = 1; d < 64; d <<= 1) avv += __shfl_xor(avv, d);
        if (lane == 0) {
            float at = isbf ? ldf<true>(attr, node) : ldf<false>(attr, node);
            float a = 0.1f * avv * at;
            cosb[node] = __cosf(a);
            sinb[node] = __sinf(a);
        }
    }
}

// ---------------- k_final ----------------
template<bool BF>
__device__ __forceinline__ void final_body(
    const void* __restrict__ ns, const void* __restrict__ nv,
    const void* __restrict__ attr,
    const float* __restrict__ Wscs, const float* __restrict__ Wscv,
    const float* __restrict__ Wl2s, const float* __restrict__ Wl2v,
    const float* __restrict__ agg_s, const float* __restrict__ agg_v,
    const float* __restrict__ cosb, const float* __restrict__ sinb,
    void* __restrict__ out, int Nn)
{
    int i = blockIdx.x * 256 + threadIdx.x;
    int stotal = Nn * MUL0;
    if (i < stotal) {
        int n = i >> 6, j = i & 63;
        const float* ar = agg_s + (size_t)n * MIDS;
        float a1 = 0.f, a2 = 0.f;
        #pragma unroll
        for (int u = 0; u < MUL0; u++)
            a1 = fmaf(ldf<BF>(ns, (size_t)n * MUL0 + u), Wscs[u * MUL0 + j], a1);
        #pragma unroll
        for (int u = 0; u < MIDS; u++) a2 = fmaf(ar[u], Wl2s[u * MUL0 + j], a2);
        float o = ldf<BF>(attr, n) * (cosb[n] * a1 + sinb[n] * a2);
        stf<BF>(out, (size_t)n * 160 + j, o);
    } else {
        int m = i - stotal;
        if (m >= Nn * 96) return;
        int n = m / 96; int idx = m - n * 96;
        int vi = idx / 3; int c = idx - vi * 3;
        const float* ar = agg_v + (size_t)n * (MIDV * 3);
        float a1 = 0.f, a2 = 0.f;
        #pragma unroll
        for (int u = 0; u < MUL1; u++)
            a1 = fmaf(ldf<BF>(nv, (size_t)n * 96 + u * 3 + c), Wscv[u * MUL1 + vi], a1);
        #pragma unroll
        for (int u = 0; u < MIDV; u++) a2 = fmaf(ar[u * 3 + c], Wl2v[u * MUL1 + vi], a2);
        float o = ldf<BF>(attr, n) * (cosb[n] * a1 + sinb[n] * a2);
        stf<BF>(out, (size_t)n * 160 + 64 + idx, o);
    }
}
__global__ __launch_bounds__(256) void k_final(
    const void* ns, const void* nv, const void* attr,
    const float* Wscs, const float* Wscv,
    const float* Wl2s, const float* Wl2v,
    const float* agg_s, const float* agg_v,
    const float* cosb, const float* sinb,
    void* out, int Nn, const int* flag)
{
    if (*flag) final_body<true >(ns, nv, attr, Wscs, Wscv, Wl2s, Wl2v, agg_s, agg_v, cosb, sinb, out, Nn);
    else       final_body<false>(ns, nv, attr, Wscs, Wscv, Wl2s, Wl2v, agg_s, agg_v, cosb, sinb, out, Nn);
}

// ---------------- launch ----------------
extern "C" void kernel_launch(void* const* d_in, const int* in_sizes, int n_in,
                              void* d_out, int out_size, void* d_ws, size_t ws_size,
                              hipStream_t stream)
{
    const void* ns    = d_in[0];
    const void* nv    = d_in[1];
    const void* attr  = d_in[2];
    const int*  esrc  = (const int*)d_in[3];
    const int*  edst  = (const int*)d_in[4];
    const void* eattr = d_in[5];
    const void* escal = d_in[6];

    const int Nn   = in_sizes[2];
    const int Ecnt = in_sizes[3];

    float* ws = (float*)d_ws;
    int* flag = (int*)(ws + OFF_FLAG);
    unsigned short* w1frag = (unsigned short*)(ws + OFF_W1FRAG);
    unsigned short* w2frag = (unsigned short*)(ws + OFF_W2FRAG);

    size_t o = OFF_DYN;
    const size_t OFF_FS   = o; o += (size_t)Nn * 64;
    const size_t OFF_FV   = o; o += (size_t)Nn * 96;
    const size_t OFF_AGGS = o; o += (size_t)Nn * 96;
    const size_t OFF_AGGV = o; o += (size_t)Nn * 384;
    const size_t OFF_COS  = o; o += Nn;
    const size_t OFF_SIN  = o; o += Nn;
    const size_t OFF_CNT  = o; o += Nn;
    const size_t OFF_ROW  = o; o += Nn + 1;
    const size_t OFF_CUR  = o; o += Nn;
    const size_t OFF_RPART= o; o += Nn;
    const size_t OFF_BSUM = o; o += 256;
    const size_t OFF_BOFF = o; o += 256;
    const size_t OFF_PERM = o; o += Ecnt;
    const size_t OFF_SRCS = o; o += Ecnt;
    o = (o + 3) & ~(size_t)3;
    const size_t OFF_Y4   = o; o += (size_t)Ecnt * 4;
    o = (o + 15) & ~(size_t)15;
    const size_t OFF_WBUF = o;
    const int tiles = (Ecnt + 63) / 64;
    o += (size_t)tiles * 64 * 112;   // 224 ushorts = 112 floats per row
    const size_t need_bytes = o * sizeof(float);

    int* cnt       = (int*)(ws + OFF_CNT);
    int* row_start = (int*)(ws + OFF_ROW);
    int* cur       = (int*)(ws + OFF_CUR);
    int* row_part  = (int*)(ws + OFF_RPART);
    int* blk_sum   = (int*)(ws + OFF_BSUM);
    int* blk_off   = (int*)(ws + OFF_BOFF);
    int* perm      = (int*)(ws + OFF_PERM);
    int* srcs      = (int*)(ws + OFF_SRCS);
    float* y4      = ws + OFF_Y4;
    unsigned short* wbuf = (unsigned short*)(ws + OFF_WBUF);

    const int NB = (Nn + 255) / 256;
    const bool split = (ws_size >= need_bytes) && (NB <= 256);

    // fused prep: probe + convert + frag build + cnt zero + node precompute
    const int prep_work = Nn * 160 + OFF_WEND + W1FRAG_N + W2FRAG_N + Nn;
    k_prep<<<(prep_work + 255) / 256, 256, 0, stream>>>(
        ns, nv, attr,
        d_in[7], d_in[8], d_in[9], d_in[10], d_in[11], d_in[12],
        d_in[13], d_in[14], d_in[15],
        ws, w1frag, w2frag, cnt, flag,
        ws + OFF_FS, ws + OFF_FV, Nn);

    k_hist<<<(Ecnt + 255) / 256, 256, 0, stream>>>(edst, cnt, Ecnt);

    if (split) {
        k_scan_blk<<<NB, 256, 0, stream>>>(cnt, row_part, blk_sum, Nn);
        k_scan_top<<<1, 256, 0, stream>>>(blk_sum, blk_off, row_start, NB, Nn);
        k_rowfix<<<NB, 256, 0, stream>>>(row_part, blk_off, row_start, cur, Nn);
        k_place<<<(Ecnt + 255) / 256, 256, 0, stream>>>(
            edst, esrc, eattr, row_start, cur, perm, srcs, y4, Ecnt, flag, 1);

        k_fc<<<tiles, 256, 0, stream>>>(escal, perm, w1frag, w2frag, wbuf, Ecnt, flag);

        k_agg<<<(Nn + EG - 1) / EG, 256, 0, stream>>>(
            wbuf, srcs, y4, row_start,
            ws + OFF_FS, ws + OFF_FV, ws + OFF_WL3, attr,
            ws + OFF_AGGS, ws + OFF_AGGV, ws + OFF_COS, ws + OFF_SIN,
            Nn, flag);
    } else {
        k_scan1<<<1, 1024, 0, stream>>>(cnt, row_start, cur, Nn);
        k_place<<<(Ecnt + 255) / 256, 256, 0, stream>>>(
            edst, esrc, eattr, row_start, cur, perm, srcs, y4, Ecnt, flag, 0);
        k_edge_mfma<<<(Nn + EG - 1) / EG, 256, 0, stream>>>(
            escal, eattr, attr, esrc, row_start, perm, w1frag, w2frag,
            ws + OFF_WL3,
            ws + OFF_FS, ws + OFF_FV,
            ws + OFF_AGGS, ws + OFF_AGGV, ws + OFF_COS, ws + OFF_SIN,
            Nn, flag);
    }

    k_final<<<((Nn * 160) + 255) / 256, 256, 0, stream>>>(
        ns, nv, attr,
        ws + OFF_WSCS, ws + OFF_WSCV, ws + OFF_WL2S, ws + OFF_WL2V,
        ws + OFF_AGGS, ws + OFF_AGGV, ws + OFF_COS, ws + OFF_SIN,
        (void*)d_out, Nn, flag);
}